// Round 8
// baseline (585.517 us; speedup 1.0000x reference)
//
#include <hip/hip_runtime.h>

// ---------------------------------------------------------------------------
// RPN forward, MI355X. Only batch element 7 contributes to the output.
// prepK (fused: zero-pad input 512x52x52 + weight->SGPR-layout transpose) ->
// conv3x3 v10 (lane = PIXEL, 4 px/thread (base, +640, +1280, +1920)
// amortizing the 72 per-cin weight s_loads over 288 FMAs, 8 oc/wave,
// immediate tap offsets, NO LDS, 128-thr blocks, 8 cin-split partials in
// (CS,512,2500) coalesced layout) -> reduce_leaky2 -> 1x1 heads ->
// decode/score/key -> O(N^2) rank sort -> top-6000 -> NMS bitmask
// (reference's yy2=max bug replicated) -> word-serial scan -> 300x4 boxes.
// Deterministic fp32: per-accumulator FMA chain (cin asc, taps 0..8) and CS
// reduce order bitwise-identical to v3..v9.
// ---------------------------------------------------------------------------

#define NPIX 2500      // 50*50
#define NANCH 22500    // 2500*9
#define NKEY 22528     // NANCH padded to 88*256 (sentinel tail)
#define PRE 6000
#define MASKW 94       // ceil(6000/64) usable words
#define MW 96          // storage stride in words
#define JCHUNK 1536    // j-chunk for mask kernel (24 words)
#define CS 8           // cin splits for conv3x3
#define KSLOT 8        // static kept-row load slots per block in scan
#define PW 52          // padded width
#define PSL 2704       // 52*52 padded slice

// ------ fused prep: blocks 0..511 zero-pad x; blocks 512..1087 transpose w -
// wtV[((cin*64 + ocg)*9 + t)*8 + j] = wt[ocg*8+j][cin*9+t]
__global__ __launch_bounds__(256) void prepK(
    const float* __restrict__ x,    // batch-7 base (512,50,50)
    const float* __restrict__ wt,   // (512, 4608)
    float* __restrict__ xpad,       // (512, 52, 52)
    float* __restrict__ wtV)        // (512, 64, 9, 8)
{
    __shared__ float T[64][65];
    const int bx = blockIdx.x;
    if (bx < 512) {
        const int cin = bx;
        const float* src = x + (size_t)cin * NPIX;
        float* dst = xpad + (size_t)cin * PSL;
        for (int i = threadIdx.x; i < PSL; i += 256) {
            const int pr = i / PW;
            const int pc = i - pr * PW;
            float v = 0.f;
            if (pr >= 1 && pr <= 50 && pc >= 1 && pc <= 50)
                v = src[(pr - 1) * 50 + (pc - 1)];
            dst[i] = v;
        }
        return;
    }
    const int idx  = bx - 512;           // 0..575 = 72 x 8
    const int ct0  = (idx % 72) * 64;
    const int ocb  = (idx / 72) * 64;
    const int tid  = threadIdx.x;
    const int cidx = tid & 63;
    const int r4   = tid >> 6;
    #pragma unroll
    for (int i = 0; i < 16; ++i) {
        const int o = r4 + i * 4;
        T[o][cidx] = wt[(size_t)(ocb + o) * 4608 + ct0 + cidx];
    }
    __syncthreads();
    #pragma unroll
    for (int i = 0; i < 16; ++i) {
        const int ctl = ct0 + r4 + i * 4;
        const int cin = ctl / 9;
        const int t   = ctl - cin * 9;
        const int oc  = ocb + cidx;
        wtV[(((size_t)cin * 64 + (oc >> 3)) * 9 + t) * 8 + (oc & 7)] =
            T[cidx][r4 + i * 4];
    }
}

// ---------------- conv 3x3 v10: 4 pixels/thread, padded input, no LDS ------
// grid (64 ocGroups, 5 pxPairs, 8 cin groups) x 128 thr = 5120 waves in
// 2560 WGs (10 WG/CU, under the WG-slot cap). Per cin: 36 loads at
// immediate tap offsets + 288 FMA sharing ONE batch of 72 SGPR weights
// (4x amortization of the s_load lgkm wait vs v8, 2x vs v9).
// Per-accumulator FMA order bitwise-identical to v3..v9 (cin asc, taps 0..8).
__global__ __launch_bounds__(128) void conv3x3_v10(
    const float* __restrict__ xpad, // padded batch-7 (512,52,52)
    const float* __restrict__ wtV,  // (512, 64, 9, 8)
    float* __restrict__ part2)      // (CS, 512, 2500)
{
    const int tid  = threadIdx.x;
    const int lane = tid & 63;
    const int wv   = tid >> 6;
    const int ocg  = blockIdx.x;            // 0..63 -> oc = ocg*8 + j
    const int pb   = blockIdx.y * 2 + wv;   // 0..9
    const int cing = blockIdx.z * 64;
    const int px0  = pb * 64 + lane;        // 0..639   (always valid)
    const int px1  = px0 + 640;             // 640..1279 (always valid)
    const int px2  = px0 + 1280;            // 1280..1919 (always valid)
    const int px3  = px0 + 1920;            // 1920..2559
    const bool act3 = (px3 < NPIX);
    const int r0 = px0 / 50, c0 = px0 - r0 * 50;
    const int r1 = px1 / 50, c1 = px1 - r1 * 50;
    const int r2 = px2 / 50, c2 = px2 - r2 * 50;
    const int px3c = act3 ? px3 : 0;
    const int r3 = px3c / 50, c3 = px3c - r3 * 50;

    // per-lane padded center addresses; taps are compile-time offsets
    const float* xb0 = xpad + (size_t)cing * PSL + (r0 + 1) * PW + (c0 + 1);
    const float* xb1 = xpad + (size_t)cing * PSL + (r1 + 1) * PW + (c1 + 1);
    const float* xb2 = xpad + (size_t)cing * PSL + (r2 + 1) * PW + (c2 + 1);
    const float* xb3 = xpad + (size_t)cing * PSL + (r3 + 1) * PW + (c3 + 1);

    float acc0[8], acc1[8], acc2[8], acc3[8];
    #pragma unroll
    for (int j = 0; j < 8; ++j) {
        acc0[j] = 0.f; acc1[j] = 0.f; acc2[j] = 0.f; acc3[j] = 0.f;
    }

    const float* wbase = wtV + ((size_t)cing * 64 + ocg) * 72;

    for (int cin = 0; cin < 64; ++cin) {
        float v0[9], v1[9], v2[9], v3[9];
        const float* xa = xb0 + (size_t)cin * PSL;
        const float* xb = xb1 + (size_t)cin * PSL;
        const float* xc = xb2 + (size_t)cin * PSL;
        const float* xd = xb3 + (size_t)cin * PSL;
        #pragma unroll
        for (int t = 0; t < 9; ++t) {
            const int dr = t / 3 - 1, dc = t % 3 - 1;
            v0[t] = xa[dr * PW + dc];
            v1[t] = xb[dr * PW + dc];
            v2[t] = xc[dr * PW + dc];
            v3[t] = xd[dr * PW + dc];
        }
        const float* wp = wbase + (size_t)cin * 4608;   // 64*72
        #pragma unroll
        for (int j = 0; j < 8; ++j) {
            float a = acc0[j];
            float b = acc1[j];
            float c = acc2[j];
            float d = acc3[j];
            #pragma unroll
            for (int t = 0; t < 9; ++t) {
                const float w = wp[t * 8 + j];
                a = fmaf(w, v0[t], a);
                b = fmaf(w, v1[t], b);
                c = fmaf(w, v2[t], c);
                d = fmaf(w, v3[t], d);
            }
            acc0[j] = a; acc1[j] = b; acc2[j] = c; acc3[j] = d;
        }
    }

    // coalesced: lane=px contiguous per oc row
    float* dst = part2 + ((size_t)blockIdx.z * 512 + ocg * 8) * NPIX;
    #pragma unroll
    for (int j = 0; j < 8; ++j) {
        dst[(size_t)j * NPIX + px0] = acc0[j];
        dst[(size_t)j * NPIX + px1] = acc1[j];
        dst[(size_t)j * NPIX + px2] = acc2[j];
    }
    if (act3) {
        #pragma unroll
        for (int j = 0; j < 8; ++j)
            dst[(size_t)j * NPIX + px3] = acc3[j];
    }
}

// ---------------- reduce partials + bias + leaky (coalesced) ---------------
__global__ __launch_bounds__(256) void reduce_leaky2(
    const float* __restrict__ part2, const float* __restrict__ bias,
    float* __restrict__ feat)
{
    const int oc = blockIdx.y;
    const int px = blockIdx.x * 256 + threadIdx.x;
    if (px >= NPIX) return;
    float s = 0.f;
    #pragma unroll
    for (int k = 0; k < CS; ++k)
        s += part2[((size_t)k * 512 + oc) * NPIX + px];
    s += bias[oc];
    s = (s >= 0.f) ? s : 0.01f * s;
    feat[(size_t)oc * NPIX + px] = s;
}

// ---------------- 1x1 heads: 4-wave cin split + LDS tree reduce ------------
__global__ __launch_bounds__(256) void conv1x1_heads(
    const float* __restrict__ feat,
    const float* __restrict__ rw, const float* __restrict__ rb,
    const float* __restrict__ cw, const float* __restrict__ cb,
    float* __restrict__ regcls)   // (54, 2500)
{
    __shared__ float sAcc[3][18][64];
    const int tid  = threadIdx.x;
    const int lane = tid & 63;
    const int wv   = tid >> 6;
    const int pix0 = blockIdx.x * 64 + lane;
    const bool act = (pix0 < NPIX);
    const int pix  = act ? pix0 : (NPIX - 1);
    const int chunk = blockIdx.y;
    const float* wb; const float* bb; int ocbase;
    if (chunk == 0)      { wb = rw;            bb = rb;      ocbase = 0;  }
    else if (chunk == 1) { wb = rw + 18 * 512; bb = rb + 18; ocbase = 18; }
    else                 { wb = cw;            bb = cb;      ocbase = 36; }

    float acc[18];
    #pragma unroll
    for (int k = 0; k < 18; ++k) acc[k] = 0.f;

    const int c0 = wv * 128;
    for (int cin = c0; cin < c0 + 128; ++cin) {
        const float v = feat[(size_t)cin * NPIX + pix];
        #pragma unroll
        for (int k = 0; k < 18; ++k)
            acc[k] = fmaf(wb[k * 512 + cin], v, acc[k]);
    }
    if (wv > 0) {
        #pragma unroll
        for (int k = 0; k < 18; ++k) sAcc[wv - 1][k][lane] = acc[k];
    }
    __syncthreads();
    if (wv == 0 && act) {
        #pragma unroll
        for (int k = 0; k < 18; ++k) {
            float s = acc[k];
            s += sAcc[0][k][lane];
            s += sAcc[1][k][lane];
            s += sAcc[2][k][lane];
            regcls[(size_t)(ocbase + k) * NPIX + pix] = s + bb[k];
        }
    }
}

// ---------------- decode: anchors, softmax score, sortable key -------------
__global__ __launch_bounds__(256) void decodeK(
    const float* __restrict__ regcls,
    float4* __restrict__ boxes,
    unsigned long long* __restrict__ keys)
{
    const int i = blockIdx.x * 256 + threadIdx.x;
    if (i >= NANCH) {
        if (i < NKEY) keys[i] = 0xFFFFFFFFFFFFFFFFull;  // sentinel: > all keys
        return;
    }
    const int pos = i / 9;
    const int a   = i - pos * 9;
    const int hh  = pos / 50;
    const int wwp = pos - hh * 50;
    const int r = a / 3, s = a - r * 3;

    const float base_s[3] = {128.f, 256.f, 512.f};
    const float sq [3] = {0.70710678118654752440f, 1.0f, 1.41421356237309504880f};
    const float sqi[3] = {1.41421356237309504880f, 1.0f, 0.70710678118654752440f};
    const float hs = base_s[s] * sq[r];
    const float ws = base_s[s] * sqi[r];
    const float cx = (float)(hh * 16 + 8);    // cx indexed by h (reference quirk)
    const float cy = (float)(wwp * 16 + 8);
    const float ax = cx - ws * 0.5f;
    const float ay = cy - hs * 0.5f;

    const float pr0 = regcls[(size_t)(a * 4 + 0) * NPIX + pos];
    const float pr1 = regcls[(size_t)(a * 4 + 1) * NPIX + pos];
    const float pr2 = regcls[(size_t)(a * 4 + 2) * NPIX + pos];
    const float pr3 = regcls[(size_t)(a * 4 + 3) * NPIX + pos];
    const float c0  = regcls[(size_t)(36 + a * 2 + 0) * NPIX + pos];
    const float c1  = regcls[(size_t)(36 + a * 2 + 1) * NPIX + pos];

    const float m  = fmaxf(c0, c1);
    const float e0 = expf(c0 - m);
    const float e1 = expf(c1 - m);
    const float score = e1 / (e0 + e1);

    const float t0 = pr0 + ax;
    const float t1 = pr1 + ay;
    const float hi = 799.0f;
    const float rx1 = fminf(fmaxf(t0, 0.f), hi);
    const float ry1 = fminf(fmaxf(t1, 0.f), hi);
    const float rx2 = fminf(fmaxf((t0 + pr2) + ws, 0.f), hi);
    const float ry2 = fminf(fmaxf((t1 + pr3) + hs, 0.f), hi);
    const float bw = pr2 + ws;
    const float bh = pr3 + hs;
    const bool valid = (bw >= 16.f) && (bh >= 16.f);
    const float sc = valid ? score : -__builtin_inff();

    unsigned u = __float_as_uint(sc);
    u = (u & 0x80000000u) ? ~u : (u | 0x80000000u);  // monotone ascending map
    const unsigned k32 = ~u;                          // descending score
    keys[i]  = ((unsigned long long)k32 << 32) | (unsigned)i;  // tie: asc index
    boxes[i] = make_float4(rx1, ry1, rx2, ry2);
}

// ---------------- O(N^2) rank (stable argsort position) --------------------
__global__ __launch_bounds__(256) void rankK(
    const unsigned long long* __restrict__ keys, int* __restrict__ rank)
{
    const int i = blockIdx.x * 256 + threadIdx.x;
    const unsigned long long my = (i < NANCH) ? keys[i] : 0ull;
    const unsigned long long* kj = keys + blockIdx.y * 2816;
    int cnt = 0;
    for (int t = 0; t < 2816; t += 8) {
        #pragma unroll
        for (int q = 0; q < 8; ++q)
            cnt += (kj[t + q] < my) ? 1 : 0;
    }
    if (i < NANCH) atomicAdd(&rank[i], cnt);
}

__global__ __launch_bounds__(256) void scatterK(
    const float4* __restrict__ boxes, const int* __restrict__ rank,
    float4* __restrict__ sboxes)
{
    const int i = blockIdx.x * 256 + threadIdx.x;
    if (i < NANCH) {
        const int r = rank[i];
        if (r < PRE) sboxes[r] = boxes[i];
    }
}

// ---------------- NMS suppression bitmask (reference bug replicated) -------
__global__ __launch_bounds__(256) void nmsMaskK(
    const float4* __restrict__ sb, unsigned long long* __restrict__ mask)
{
    __shared__ float sx1[JCHUNK], sy1[JCHUNK], sx2[JCHUNK], sy2[JCHUNK], sar[JCHUNK];
    const int tid = threadIdx.x;
    const int jbase = blockIdx.y * JCHUNK;
    for (int t = tid; t < JCHUNK; t += 256) {
        const int j = jbase + t;
        if (j < PRE) {
            const float4 b = sb[j];
            sx1[t] = b.x; sy1[t] = b.y; sx2[t] = b.z; sy2[t] = b.w;
            sar[t] = (b.z - b.x + 1.f) * (b.w - b.y + 1.f);
        } else {
            sx1[t] = 0.f; sy1[t] = 0.f; sx2[t] = -1.f; sy2[t] = 0.f; sar[t] = 0.f;
        }
    }
    __syncthreads();
    const int i = blockIdx.x * 16 + (tid >> 4);
    const float4 bi = sb[i];
    const float x1 = bi.x, y1 = bi.y, x2 = bi.z, y2 = bi.w;
    const float ar = (x2 - x1 + 1.f) * (y2 - y1 + 1.f);
    for (int w = (tid & 15); w < 24; w += 16) {
        unsigned long long bits = 0ull;
        const int l0 = w * 64;
        for (int u = 0; u < 64; ++u) {
            const int j = jbase + l0 + u;
            if (j > i && j < PRE) {
                const int l = l0 + u;
                const float xx1 = fmaxf(x1, sx1[l]);
                const float yy1 = fmaxf(y1, sy1[l]);
                const float xx2 = fminf(x2, sx2[l]);
                const float yy2 = fmaxf(y2, sy2[l]);        // reference bug: max
                const float wv = fmaxf(0.f, xx2 - xx1 + 1.f);
                const float hv = fmaxf(0.f, yy2 - yy1 + 1.f);
                const float inter = wv * hv;
                const float ov = inter / ((ar + sar[l]) - inter);  // precise div
                if (ov > 0.7f) bits |= (1ull << u);
            }
        }
        mask[(size_t)i * MW + blockIdx.y * 24 + w] = bits;
    }
}

// ---------------- word-serial NMS scan + output (single wave) --------------
// Per 64-candidate block g: (1) pure-ALU in-block loop using ONLY the diag
// word (every iteration keeps exactly one box; suppression via diag
// readlanes); (2) batched loads of the ~3 actually-kept rows (<=KSLOT static
// slots + rare overflow), one wait, OR into register-resident rem.
__global__ __launch_bounds__(64) void nmsScanOutK(
    const unsigned long long* __restrict__ mask,
    const float4* __restrict__ sb,
    float* __restrict__ out)
{
    __shared__ int sKept[300];
    __shared__ unsigned long long sKeepW[MASKW];
    const int lane = threadIdx.x;

    unsigned long long rem0 = 0ull, rem1 = 0ull;   // lane l: words l, 64+l
    int cnt = 0;
    int done = 0;

    unsigned long long diag = mask[(size_t)lane * MW + 0];   // block 0 diag

    for (int g = 0; g < MASKW && !done; ++g) {
        // prefetch next block's diagonal word (overlaps this block's work)
        unsigned long long diag_next = 0ull;
        if (g + 1 < MASKW) {
            const int r2 = (g + 1) * 64 + lane;
            if (r2 < PRE) diag_next = mask[(size_t)r2 * MW + (g + 1)];
        }
        // initial suppression word for this block (broadcast from rem)
        unsigned long long cur;
        {
            unsigned lo, hi;
            if (g < 64) {
                lo = __builtin_amdgcn_readlane((unsigned)rem0, g);
                hi = __builtin_amdgcn_readlane((unsigned)(rem0 >> 32), g);
            } else {
                lo = __builtin_amdgcn_readlane((unsigned)rem1, g - 64);
                hi = __builtin_amdgcn_readlane((unsigned)(rem1 >> 32), g - 64);
            }
            cur = ((unsigned long long)hi << 32) | lo;
        }
        const unsigned long long valid =
            (g == MASKW - 1) ? 0x0000FFFFFFFFFFFFull : ~0ull;   // 48 tail bits

        // ---- in-block serial loop: pure ALU, zero memory ops ----
        unsigned long long kb = 0ull;
        for (;;) {
            const unsigned long long nd = (~cur) & valid;
            if (!nd) break;
            const int b = __builtin_ctzll(nd);     // unsuppressed => KEPT
            if (lane == 0 && cnt < 300) sKept[cnt] = g * 64 + b;
            ++cnt;
            kb |= (1ull << b);
            if (cnt >= 300) { done = 1; break; }
            const unsigned dlo = __builtin_amdgcn_readlane((unsigned)diag, b);
            const unsigned dhi = __builtin_amdgcn_readlane((unsigned)(diag >> 32), b);
            cur |= (1ull << b) | (((unsigned long long)dhi << 32) | dlo);
        }
        if (lane == 0) sKeepW[g] = kb;

        // ---- batched kept-row loads: OR their full rows into rem ----
        if (!done && kb) {
            int kbit[KSLOT];
            unsigned long long t = kb;
            #pragma unroll
            for (int s = 0; s < KSLOT; ++s) {
                kbit[s] = t ? __builtin_ctzll(t) : 64;
                t &= t - 1;
            }
            unsigned long long a0 = 0ull, a1 = 0ull;
            #pragma unroll
            for (int s = 0; s < KSLOT; ++s) {
                if (kbit[s] < 64) {                // wave-uniform branch
                    const unsigned long long* pr =
                        mask + (size_t)(g * 64 + kbit[s]) * MW;
                    a0 |= pr[lane];
                    a1 |= (lane < MASKW - 64) ? pr[64 + lane] : 0ull;
                }
            }
            while (t) {                             // >KSLOT overflow (rare)
                const int b = __builtin_ctzll(t); t &= t - 1;
                const unsigned long long* pr = mask + (size_t)(g * 64 + b) * MW;
                a0 |= pr[lane];
                a1 |= (lane < MASKW - 64) ? pr[64 + lane] : 0ull;
            }
            rem0 |= a0;
            rem1 |= a1;
        }
        diag = diag_next;
    }

    __syncthreads();

    if (cnt < 300) {                                 // filler: unkept, asc index
        int c = cnt;
        for (int g = 0; g < MASKW && c < 300; ++g) {
            const unsigned long long valid =
                (g == MASKW - 1) ? 0x0000FFFFFFFFFFFFull : ~0ull;
            unsigned long long u = (~sKeepW[g]) & valid;
            while (u && c < 300) {
                const int b = __builtin_ctzll(u); u &= u - 1;
                if (lane == 0) sKept[c] = g * 64 + b;
                ++c;
            }
        }
    }
    __syncthreads();

    for (int s = lane; s < 300; s += 64) {
        const float4 b = sb[sKept[s]];
        out[s * 4 + 0] = b.x;
        out[s * 4 + 1] = b.y;
        out[s * 4 + 2] = b.z - b.x + 1.0f;
        out[s * 4 + 3] = b.w - b.y + 1.0f;
    }
}

// ---------------------------------------------------------------------------
extern "C" void kernel_launch(void* const* d_in, const int* in_sizes, int n_in,
                              void* d_out, int out_size, void* d_ws, size_t ws_size,
                              hipStream_t stream)
{
    (void)in_sizes; (void)n_in; (void)out_size; (void)ws_size;
    const float* x   = (const float*)d_in[0] + (size_t)7 * 512 * NPIX; // batch 7
    const float* cw3 = (const float*)d_in[1];
    const float* cb3 = (const float*)d_in[2];
    const float* rw  = (const float*)d_in[3];
    const float* rb  = (const float*)d_in[4];
    const float* clw = (const float*)d_in[5];
    const float* clb = (const float*)d_in[6];
    float* out = (float*)d_out;

    char* p = (char*)d_ws;
    auto alloc = [&](size_t n) { char* r = p; p += (n + 255) & ~(size_t)255; return r; };
    float*  part2  = (float*)alloc((size_t)CS * 512 * NPIX * 4);  // 41 MB
    float*  wtV    = (float*)alloc((size_t)4608 * 512 * 4);       // 9.4 MB
    float*  xpad   = (float*)alloc((size_t)512 * PSL * 4);        // 5.5 MB
    float*  feat   = (float*)alloc((size_t)512 * NPIX * 4);       // 5.12 MB
    float*  regcls = (float*)alloc((size_t)54 * NPIX * 4);        // 0.54 MB
    float4* boxes  = (float4*)alloc((size_t)NANCH * 16);          // 0.36 MB
    unsigned long long* keys = (unsigned long long*)alloc((size_t)NKEY * 8);
    int*    rank   = (int*)alloc((size_t)NANCH * 4);
    float4* sboxes = (float4*)alloc((size_t)PRE * 16);
    unsigned long long* mask = (unsigned long long*)alloc((size_t)PRE * MW * 8); // 4.6 MB

    hipMemsetAsync(rank, 0, (size_t)NANCH * 4, stream);
    prepK         <<<1088, 256, 0, stream>>>(x, cw3, xpad, wtV);
    conv3x3_v10   <<<dim3(64, 5, CS), 128, 0, stream>>>(xpad, wtV, part2);
    reduce_leaky2 <<<dim3(10, 512), 256, 0, stream>>>(part2, cb3, feat);
    conv1x1_heads <<<dim3(40, 3), 256, 0, stream>>>(feat, rw, rb, clw, clb, regcls);
    decodeK       <<<88, 256, 0, stream>>>(regcls, boxes, keys);
    rankK         <<<dim3(88, 8), 256, 0, stream>>>(keys, rank);
    scatterK      <<<88, 256, 0, stream>>>(boxes, rank, sboxes);
    nmsMaskK      <<<dim3(375, 4), 256, 0, stream>>>(sboxes, mask);
    nmsScanOutK   <<<1, 64, 0, stream>>>(mask, sboxes, out);
}

// Round 9
// 573.857 us; speedup vs baseline: 1.0203x; 1.0203x over previous
//
#include <hip/hip_runtime.h>

// ---------------------------------------------------------------------------
// RPN forward, MI355X. Only batch element 7 contributes to the output.
// prepK (fused: zero-pad input 512x52x52 + weight->SGPR-layout transpose) ->
// conv3x3 v9 (lane = PIXEL, 2 px/thread, 72 SGPR weights / 144 FMA per cin,
// immediate tap offsets, NO LDS) -> reduce_leaky4 (float4) -> 1x1 heads ->
// decode/score/key -> O(N^2) rank sort -> top-6000 -> NMS bitmask
// (reference's yy2=max bug replicated) -> PAIRED word-serial scan (2 blocks
// = 128 candidates per round via diag+superdiag, 47 serial rounds vs 94) ->
// 300x4 boxes. Deterministic fp32: per-accumulator FMA chain (cin asc,
// taps 0..8) and CS reduce order bitwise-identical to v3..v9.
// ---------------------------------------------------------------------------

#define NPIX 2500      // 50*50
#define NANCH 22500    // 2500*9
#define NKEY 22528     // NANCH padded to 88*256 (sentinel tail)
#define PRE 6000
#define MASKW 94       // ceil(6000/64) usable words
#define MW 96          // storage stride in words
#define JCHUNK 1536    // j-chunk for mask kernel (24 words)
#define CS 8           // cin splits for conv3x3
#define KSLOT 8        // static kept-row load slots per word in scan
#define PW 52          // padded width
#define PSL 2704       // 52*52 padded slice

// ------ fused prep: blocks 0..511 zero-pad x; blocks 512..1087 transpose w -
// wtV[((cin*64 + ocg)*9 + t)*8 + j] = wt[ocg*8+j][cin*9+t]
__global__ __launch_bounds__(256) void prepK(
    const float* __restrict__ x,    // batch-7 base (512,50,50)
    const float* __restrict__ wt,   // (512, 4608)
    float* __restrict__ xpad,       // (512, 52, 52)
    float* __restrict__ wtV)        // (512, 64, 9, 8)
{
    __shared__ float T[64][65];
    const int bx = blockIdx.x;
    if (bx < 512) {
        const int cin = bx;
        const float* src = x + (size_t)cin * NPIX;
        float* dst = xpad + (size_t)cin * PSL;
        for (int i = threadIdx.x; i < PSL; i += 256) {
            const int pr = i / PW;
            const int pc = i - pr * PW;
            float v = 0.f;
            if (pr >= 1 && pr <= 50 && pc >= 1 && pc <= 50)
                v = src[(pr - 1) * 50 + (pc - 1)];
            dst[i] = v;
        }
        return;
    }
    const int idx  = bx - 512;           // 0..575 = 72 x 8
    const int ct0  = (idx % 72) * 64;
    const int ocb  = (idx / 72) * 64;
    const int tid  = threadIdx.x;
    const int cidx = tid & 63;
    const int r4   = tid >> 6;
    #pragma unroll
    for (int i = 0; i < 16; ++i) {
        const int o = r4 + i * 4;
        T[o][cidx] = wt[(size_t)(ocb + o) * 4608 + ct0 + cidx];
    }
    __syncthreads();
    #pragma unroll
    for (int i = 0; i < 16; ++i) {
        const int ctl = ct0 + r4 + i * 4;
        const int cin = ctl / 9;
        const int t   = ctl - cin * 9;
        const int oc  = ocb + cidx;
        wtV[(((size_t)cin * 64 + (oc >> 3)) * 9 + t) * 8 + (oc & 7)] =
            T[cidx][r4 + i * 4];
    }
}

// ---------------- conv 3x3 v9: 2 pixels/thread, padded input, no LDS -------
// grid (64 ocGroups, 5 pxOcts, 8 cin groups) x 256 thr = 10240 waves.
// Per cin: 18 loads at immediate tap offsets + 144 FMA sharing ONE batch of
// 72 SGPR weights. Per-accumulator FMA order bitwise-identical (cin asc,
// taps 0..8).
__global__ __launch_bounds__(256) void conv3x3_v9(
    const float* __restrict__ xpad, // padded batch-7 (512,52,52)
    const float* __restrict__ wtV,  // (512, 64, 9, 8)
    float* __restrict__ part2)      // (CS, 512, 2500)
{
    const int tid  = threadIdx.x;
    const int lane = tid & 63;
    const int wv   = tid >> 6;
    const int ocg  = blockIdx.x;            // 0..63 -> oc = ocg*8 + j
    const int pb   = blockIdx.y * 4 + wv;   // 0..19
    const int cing = blockIdx.z * 64;
    const int px0  = pb * 64 + lane;        // 0..1279 (always valid)
    const int px1  = px0 + 1280;            // 1280..2559
    const bool act1 = (px1 < NPIX);
    const int r0 = px0 / 50, cc0 = px0 - r0 * 50;
    const int px1c = act1 ? px1 : 0;
    const int r1 = px1c / 50, cc1 = px1c - r1 * 50;

    const float* xb0 = xpad + (size_t)cing * PSL + (r0 + 1) * PW + (cc0 + 1);
    const float* xb1 = xpad + (size_t)cing * PSL + (r1 + 1) * PW + (cc1 + 1);

    float acc0[8], acc1[8];
    #pragma unroll
    for (int j = 0; j < 8; ++j) { acc0[j] = 0.f; acc1[j] = 0.f; }

    const float* wbase = wtV + ((size_t)cing * 64 + ocg) * 72;

    for (int cin = 0; cin < 64; ++cin) {
        float v0[9], v1[9];
        const float* xa = xb0 + (size_t)cin * PSL;
        const float* xc = xb1 + (size_t)cin * PSL;
        #pragma unroll
        for (int t = 0; t < 9; ++t) {
            const int dr = t / 3 - 1, dc = t % 3 - 1;
            v0[t] = xa[dr * PW + dc];
            v1[t] = xc[dr * PW + dc];
        }
        const float* wp = wbase + (size_t)cin * 4608;   // 64*72
        #pragma unroll
        for (int j = 0; j < 8; ++j) {
            float a = acc0[j];
            float b = acc1[j];
            #pragma unroll
            for (int t = 0; t < 9; ++t) {
                const float w = wp[t * 8 + j];
                a = fmaf(w, v0[t], a);
                b = fmaf(w, v1[t], b);
            }
            acc0[j] = a;
            acc1[j] = b;
        }
    }

    float* dst0 = part2 + ((size_t)blockIdx.z * 512 + ocg * 8) * NPIX + px0;
    #pragma unroll
    for (int j = 0; j < 8; ++j)
        dst0[(size_t)j * NPIX] = acc0[j];
    if (act1) {
        float* dst1 = part2 + ((size_t)blockIdx.z * 512 + ocg * 8) * NPIX + px1;
        #pragma unroll
        for (int j = 0; j < 8; ++j)
            dst1[(size_t)j * NPIX] = acc1[j];
    }
}

// ------------ reduce partials + bias + leaky (float4 vectorized) -----------
// 2500 = 625 float4; per-element k-ascending sum + bias + leaky: identical
// arithmetic order to the scalar version (bitwise).
__global__ __launch_bounds__(256) void reduce_leaky4(
    const float* __restrict__ part2, const float* __restrict__ bias,
    float* __restrict__ feat)
{
    const int oc = blockIdx.x;
    const float b = bias[oc];
    float4* dstv = (float4*)(feat + (size_t)oc * NPIX);
    for (int q = threadIdx.x; q < 625; q += 256) {
        float4 s = make_float4(0.f, 0.f, 0.f, 0.f);
        #pragma unroll
        for (int k = 0; k < CS; ++k) {
            const float4 v = *(const float4*)(part2 + ((size_t)k * 512 + oc) * NPIX + q * 4);
            s.x += v.x; s.y += v.y; s.z += v.z; s.w += v.w;
        }
        s.x += b; s.y += b; s.z += b; s.w += b;
        s.x = (s.x >= 0.f) ? s.x : 0.01f * s.x;
        s.y = (s.y >= 0.f) ? s.y : 0.01f * s.y;
        s.z = (s.z >= 0.f) ? s.z : 0.01f * s.z;
        s.w = (s.w >= 0.f) ? s.w : 0.01f * s.w;
        dstv[q] = s;
    }
}

// ---------------- 1x1 heads: 4-wave cin split + LDS tree reduce ------------
__global__ __launch_bounds__(256) void conv1x1_heads(
    const float* __restrict__ feat,
    const float* __restrict__ rw, const float* __restrict__ rb,
    const float* __restrict__ cw, const float* __restrict__ cb,
    float* __restrict__ regcls)   // (54, 2500)
{
    __shared__ float sAcc[3][18][64];
    const int tid  = threadIdx.x;
    const int lane = tid & 63;
    const int wv   = tid >> 6;
    const int pix0 = blockIdx.x * 64 + lane;
    const bool act = (pix0 < NPIX);
    const int pix  = act ? pix0 : (NPIX - 1);
    const int chunk = blockIdx.y;
    const float* wb; const float* bb; int ocbase;
    if (chunk == 0)      { wb = rw;            bb = rb;      ocbase = 0;  }
    else if (chunk == 1) { wb = rw + 18 * 512; bb = rb + 18; ocbase = 18; }
    else                 { wb = cw;            bb = cb;      ocbase = 36; }

    float acc[18];
    #pragma unroll
    for (int k = 0; k < 18; ++k) acc[k] = 0.f;

    const int c0 = wv * 128;
    for (int cin = c0; cin < c0 + 128; ++cin) {
        const float v = feat[(size_t)cin * NPIX + pix];
        #pragma unroll
        for (int k = 0; k < 18; ++k)
            acc[k] = fmaf(wb[k * 512 + cin], v, acc[k]);
    }
    if (wv > 0) {
        #pragma unroll
        for (int k = 0; k < 18; ++k) sAcc[wv - 1][k][lane] = acc[k];
    }
    __syncthreads();
    if (wv == 0 && act) {
        #pragma unroll
        for (int k = 0; k < 18; ++k) {
            float s = acc[k];
            s += sAcc[0][k][lane];
            s += sAcc[1][k][lane];
            s += sAcc[2][k][lane];
            regcls[(size_t)(ocbase + k) * NPIX + pix] = s + bb[k];
        }
    }
}

// ---------------- decode: anchors, softmax score, sortable key -------------
__global__ __launch_bounds__(256) void decodeK(
    const float* __restrict__ regcls,
    float4* __restrict__ boxes,
    unsigned long long* __restrict__ keys)
{
    const int i = blockIdx.x * 256 + threadIdx.x;
    if (i >= NANCH) {
        if (i < NKEY) keys[i] = 0xFFFFFFFFFFFFFFFFull;  // sentinel: > all keys
        return;
    }
    const int pos = i / 9;
    const int a   = i - pos * 9;
    const int hh  = pos / 50;
    const int wwp = pos - hh * 50;
    const int r = a / 3, s = a - r * 3;

    const float base_s[3] = {128.f, 256.f, 512.f};
    const float sq [3] = {0.70710678118654752440f, 1.0f, 1.41421356237309504880f};
    const float sqi[3] = {1.41421356237309504880f, 1.0f, 0.70710678118654752440f};
    const float hs = base_s[s] * sq[r];
    const float ws = base_s[s] * sqi[r];
    const float cx = (float)(hh * 16 + 8);    // cx indexed by h (reference quirk)
    const float cy = (float)(wwp * 16 + 8);
    const float ax = cx - ws * 0.5f;
    const float ay = cy - hs * 0.5f;

    const float pr0 = regcls[(size_t)(a * 4 + 0) * NPIX + pos];
    const float pr1 = regcls[(size_t)(a * 4 + 1) * NPIX + pos];
    const float pr2 = regcls[(size_t)(a * 4 + 2) * NPIX + pos];
    const float pr3 = regcls[(size_t)(a * 4 + 3) * NPIX + pos];
    const float c0  = regcls[(size_t)(36 + a * 2 + 0) * NPIX + pos];
    const float c1  = regcls[(size_t)(36 + a * 2 + 1) * NPIX + pos];

    const float m  = fmaxf(c0, c1);
    const float e0 = expf(c0 - m);
    const float e1 = expf(c1 - m);
    const float score = e1 / (e0 + e1);

    const float t0 = pr0 + ax;
    const float t1 = pr1 + ay;
    const float hi = 799.0f;
    const float rx1 = fminf(fmaxf(t0, 0.f), hi);
    const float ry1 = fminf(fmaxf(t1, 0.f), hi);
    const float rx2 = fminf(fmaxf((t0 + pr2) + ws, 0.f), hi);
    const float ry2 = fminf(fmaxf((t1 + pr3) + hs, 0.f), hi);
    const float bw = pr2 + ws;
    const float bh = pr3 + hs;
    const bool valid = (bw >= 16.f) && (bh >= 16.f);
    const float sc = valid ? score : -__builtin_inff();

    unsigned u = __float_as_uint(sc);
    u = (u & 0x80000000u) ? ~u : (u | 0x80000000u);  // monotone ascending map
    const unsigned k32 = ~u;                          // descending score
    keys[i]  = ((unsigned long long)k32 << 32) | (unsigned)i;  // tie: asc index
    boxes[i] = make_float4(rx1, ry1, rx2, ry2);
}

// ---------------- O(N^2) rank (stable argsort position) --------------------
__global__ __launch_bounds__(256) void rankK(
    const unsigned long long* __restrict__ keys, int* __restrict__ rank)
{
    const int i = blockIdx.x * 256 + threadIdx.x;
    const unsigned long long my = (i < NANCH) ? keys[i] : 0ull;
    const unsigned long long* kj = keys + blockIdx.y * 2816;
    int cnt = 0;
    for (int t = 0; t < 2816; t += 8) {
        #pragma unroll
        for (int q = 0; q < 8; ++q)
            cnt += (kj[t + q] < my) ? 1 : 0;
    }
    if (i < NANCH) atomicAdd(&rank[i], cnt);
}

__global__ __launch_bounds__(256) void scatterK(
    const float4* __restrict__ boxes, const int* __restrict__ rank,
    float4* __restrict__ sboxes)
{
    const int i = blockIdx.x * 256 + threadIdx.x;
    if (i < NANCH) {
        const int r = rank[i];
        if (r < PRE) sboxes[r] = boxes[i];
    }
}

// ---------------- NMS suppression bitmask (reference bug replicated) -------
__global__ __launch_bounds__(256) void nmsMaskK(
    const float4* __restrict__ sb, unsigned long long* __restrict__ mask)
{
    __shared__ float sx1[JCHUNK], sy1[JCHUNK], sx2[JCHUNK], sy2[JCHUNK], sar[JCHUNK];
    const int tid = threadIdx.x;
    const int jbase = blockIdx.y * JCHUNK;
    for (int t = tid; t < JCHUNK; t += 256) {
        const int j = jbase + t;
        if (j < PRE) {
            const float4 b = sb[j];
            sx1[t] = b.x; sy1[t] = b.y; sx2[t] = b.z; sy2[t] = b.w;
            sar[t] = (b.z - b.x + 1.f) * (b.w - b.y + 1.f);
        } else {
            sx1[t] = 0.f; sy1[t] = 0.f; sx2[t] = -1.f; sy2[t] = 0.f; sar[t] = 0.f;
        }
    }
    __syncthreads();
    const int i = blockIdx.x * 16 + (tid >> 4);
    const float4 bi = sb[i];
    const float x1 = bi.x, y1 = bi.y, x2 = bi.z, y2 = bi.w;
    const float ar = (x2 - x1 + 1.f) * (y2 - y1 + 1.f);
    for (int w = (tid & 15); w < 24; w += 16) {
        unsigned long long bits = 0ull;
        const int l0 = w * 64;
        for (int u = 0; u < 64; ++u) {
            const int j = jbase + l0 + u;
            if (j > i && j < PRE) {
                const int l = l0 + u;
                const float xx1 = fmaxf(x1, sx1[l]);
                const float yy1 = fmaxf(y1, sy1[l]);
                const float xx2 = fminf(x2, sx2[l]);
                const float yy2 = fmaxf(y2, sy2[l]);        // reference bug: max
                const float wv = fmaxf(0.f, xx2 - xx1 + 1.f);
                const float hv = fmaxf(0.f, yy2 - yy1 + 1.f);
                const float inter = wv * hv;
                const float ov = inter / ((ar + sar[l]) - inter);  // precise div
                if (ov > 0.7f) bits |= (1ull << u);
            }
        }
        mask[(size_t)i * MW + blockIdx.y * 24 + w] = bits;
    }
}

// ------------- PAIRED word-serial NMS scan + output (single wave) ----------
// Processes TWO 64-candidate blocks (g0=2p, g1=2p+1) per round using three
// preloaded diagonal words: d00=row(g0)[g0], d01=row(g0)[g1] (superdiag),
// d11=row(g1)[g1]. Keeps drain g0 first then g1 (index order preserved;
// g1 keeps cannot suppress g0). 47 serial rounds instead of 94 -> half the
// exposed cross-XCD mask-row load latency. Keep set identical to the
// unpaired scan (same mask bits, same order).
__global__ __launch_bounds__(64) void nmsScanOutK(
    const unsigned long long* __restrict__ mask,
    const float4* __restrict__ sb,
    float* __restrict__ out)
{
    __shared__ int sKept[300];
    __shared__ unsigned long long sKeepW[MASKW];
    const int lane = threadIdx.x;

    unsigned long long rem0 = 0ull, rem1 = 0ull;   // lane l: words l, 64+l
    int cnt = 0;
    int done = 0;

    // preload pair 0 diagonals
    unsigned long long d00 = mask[(size_t)lane * MW + 0];
    unsigned long long d01 = mask[(size_t)lane * MW + 1];
    unsigned long long d11 = mask[(size_t)(64 + lane) * MW + 1];

    for (int p = 0; p < 47 && !done; ++p) {
        const int g0 = 2 * p, g1 = 2 * p + 1;

        // prefetch next pair's three diagonal words (overlap with this round)
        unsigned long long n00 = 0ull, n01 = 0ull, n11 = 0ull;
        if (p + 1 < 47) {
            const int h0 = g0 + 2, h1 = g0 + 3;
            const int ra = h0 * 64 + lane;
            const int rb = h1 * 64 + lane;
            n00 = mask[(size_t)ra * MW + h0];
            n01 = mask[(size_t)ra * MW + h1];
            if (rb < PRE) n11 = mask[(size_t)rb * MW + h1];
        }

        // broadcast current suppression words g0, g1 from rem
        unsigned long long cur0, cur1;
        {
            unsigned lo, hi;
            if (g0 < 64) {
                lo = __builtin_amdgcn_readlane((unsigned)rem0, g0);
                hi = __builtin_amdgcn_readlane((unsigned)(rem0 >> 32), g0);
            } else {
                lo = __builtin_amdgcn_readlane((unsigned)rem1, g0 - 64);
                hi = __builtin_amdgcn_readlane((unsigned)(rem1 >> 32), g0 - 64);
            }
            cur0 = ((unsigned long long)hi << 32) | lo;
            if (g1 < 64) {
                lo = __builtin_amdgcn_readlane((unsigned)rem0, g1);
                hi = __builtin_amdgcn_readlane((unsigned)(rem0 >> 32), g1);
            } else {
                lo = __builtin_amdgcn_readlane((unsigned)rem1, g1 - 64);
                hi = __builtin_amdgcn_readlane((unsigned)(rem1 >> 32), g1 - 64);
            }
            cur1 = ((unsigned long long)hi << 32) | lo;
        }
        const unsigned long long valid0 = ~0ull;    // g0 <= 92: always full
        const unsigned long long valid1 =
            (g1 == MASKW - 1) ? 0x0000FFFFFFFFFFFFull : ~0ull;  // 48 tail bits

        // ---- phase A: drain block g0 keeps (pure ALU) ----
        unsigned long long kb0 = 0ull, kb1 = 0ull;
        for (;;) {
            const unsigned long long nd = (~cur0) & valid0;
            if (!nd) break;
            const int b = __builtin_ctzll(nd);
            if (lane == 0 && cnt < 300) sKept[cnt] = g0 * 64 + b;
            ++cnt;
            kb0 |= (1ull << b);
            if (cnt >= 300) { done = 1; break; }
            const unsigned al = __builtin_amdgcn_readlane((unsigned)d00, b);
            const unsigned ah = __builtin_amdgcn_readlane((unsigned)(d00 >> 32), b);
            const unsigned bl = __builtin_amdgcn_readlane((unsigned)d01, b);
            const unsigned bh = __builtin_amdgcn_readlane((unsigned)(d01 >> 32), b);
            cur0 |= (1ull << b) | (((unsigned long long)ah << 32) | al);
            cur1 |= (((unsigned long long)bh << 32) | bl);
        }
        // ---- phase B: drain block g1 keeps ----
        if (!done) {
            for (;;) {
                const unsigned long long nd = (~cur1) & valid1;
                if (!nd) break;
                const int b = __builtin_ctzll(nd);
                if (lane == 0 && cnt < 300) sKept[cnt] = g1 * 64 + b;
                ++cnt;
                kb1 |= (1ull << b);
                if (cnt >= 300) { done = 1; break; }
                const unsigned cl = __builtin_amdgcn_readlane((unsigned)d11, b);
                const unsigned ch = __builtin_amdgcn_readlane((unsigned)(d11 >> 32), b);
                cur1 |= (1ull << b) | (((unsigned long long)ch << 32) | cl);
            }
        }
        if (lane == 0) { sKeepW[g0] = kb0; sKeepW[g1] = kb1; }

        // ---- batched kept-row loads for BOTH blocks, one rem update ----
        if (!done && (kb0 | kb1)) {
            unsigned long long a0 = 0ull, a1 = 0ull;
            {
                int kbit[KSLOT];
                unsigned long long t = kb0;
                #pragma unroll
                for (int s = 0; s < KSLOT; ++s) {
                    kbit[s] = t ? __builtin_ctzll(t) : 64;
                    t &= t - 1;
                }
                #pragma unroll
                for (int s = 0; s < KSLOT; ++s) {
                    if (kbit[s] < 64) {            // wave-uniform branch
                        const unsigned long long* pr =
                            mask + (size_t)(g0 * 64 + kbit[s]) * MW;
                        a0 |= pr[lane];
                        a1 |= (lane < MASKW - 64) ? pr[64 + lane] : 0ull;
                    }
                }
                while (t) {                         // >KSLOT overflow (rare)
                    const int b = __builtin_ctzll(t); t &= t - 1;
                    const unsigned long long* pr =
                        mask + (size_t)(g0 * 64 + b) * MW;
                    a0 |= pr[lane];
                    a1 |= (lane < MASKW - 64) ? pr[64 + lane] : 0ull;
                }
            }
            {
                int kbit[KSLOT];
                unsigned long long t = kb1;
                #pragma unroll
                for (int s = 0; s < KSLOT; ++s) {
                    kbit[s] = t ? __builtin_ctzll(t) : 64;
                    t &= t - 1;
                }
                #pragma unroll
                for (int s = 0; s < KSLOT; ++s) {
                    if (kbit[s] < 64) {            // wave-uniform branch
                        const unsigned long long* pr =
                            mask + (size_t)(g1 * 64 + kbit[s]) * MW;
                        a0 |= pr[lane];
                        a1 |= (lane < MASKW - 64) ? pr[64 + lane] : 0ull;
                    }
                }
                while (t) {                         // >KSLOT overflow (rare)
                    const int b = __builtin_ctzll(t); t &= t - 1;
                    const unsigned long long* pr =
                        mask + (size_t)(g1 * 64 + b) * MW;
                    a0 |= pr[lane];
                    a1 |= (lane < MASKW - 64) ? pr[64 + lane] : 0ull;
                }
            }
            rem0 |= a0;
            rem1 |= a1;
        }
        d00 = n00; d01 = n01; d11 = n11;
    }

    __syncthreads();

    if (cnt < 300) {                                 // filler: unkept, asc index
        int c = cnt;
        for (int g = 0; g < MASKW && c < 300; ++g) {
            const unsigned long long valid =
                (g == MASKW - 1) ? 0x0000FFFFFFFFFFFFull : ~0ull;
            unsigned long long u = (~sKeepW[g]) & valid;
            while (u && c < 300) {
                const int b = __builtin_ctzll(u); u &= u - 1;
                if (lane == 0) sKept[c] = g * 64 + b;
                ++c;
            }
        }
    }
    __syncthreads();

    for (int s = lane; s < 300; s += 64) {
        const float4 b = sb[sKept[s]];
        out[s * 4 + 0] = b.x;
        out[s * 4 + 1] = b.y;
        out[s * 4 + 2] = b.z - b.x + 1.0f;
        out[s * 4 + 3] = b.w - b.y + 1.0f;
    }
}

// ---------------------------------------------------------------------------
extern "C" void kernel_launch(void* const* d_in, const int* in_sizes, int n_in,
                              void* d_out, int out_size, void* d_ws, size_t ws_size,
                              hipStream_t stream)
{
    (void)in_sizes; (void)n_in; (void)out_size; (void)ws_size;
    const float* x   = (const float*)d_in[0] + (size_t)7 * 512 * NPIX; // batch 7
    const float* cw3 = (const float*)d_in[1];
    const float* cb3 = (const float*)d_in[2];
    const float* rw  = (const float*)d_in[3];
    const float* rb  = (const float*)d_in[4];
    const float* clw = (const float*)d_in[5];
    const float* clb = (const float*)d_in[6];
    float* out = (float*)d_out;

    char* p = (char*)d_ws;
    auto alloc = [&](size_t n) { char* r = p; p += (n + 255) & ~(size_t)255; return r; };
    float*  part2  = (float*)alloc((size_t)CS * 512 * NPIX * 4);  // 41 MB
    float*  wtV    = (float*)alloc((size_t)4608 * 512 * 4);       // 9.4 MB
    float*  xpad   = (float*)alloc((size_t)512 * PSL * 4);        // 5.5 MB
    float*  feat   = (float*)alloc((size_t)512 * NPIX * 4);       // 5.12 MB
    float*  regcls = (float*)alloc((size_t)54 * NPIX * 4);        // 0.54 MB
    float4* boxes  = (float4*)alloc((size_t)NANCH * 16);          // 0.36 MB
    unsigned long long* keys = (unsigned long long*)alloc((size_t)NKEY * 8);
    int*    rank   = (int*)alloc((size_t)NANCH * 4);
    float4* sboxes = (float4*)alloc((size_t)PRE * 16);
    unsigned long long* mask = (unsigned long long*)alloc((size_t)PRE * MW * 8); // 4.6 MB

    hipMemsetAsync(rank, 0, (size_t)NANCH * 4, stream);
    prepK         <<<1088, 256, 0, stream>>>(x, cw3, xpad, wtV);
    conv3x3_v9    <<<dim3(64, 5, CS), 256, 0, stream>>>(xpad, wtV, part2);
    reduce_leaky4 <<<512, 256, 0, stream>>>(part2, cb3, feat);
    conv1x1_heads <<<dim3(40, 3), 256, 0, stream>>>(feat, rw, rb, clw, clb, regcls);
    decodeK       <<<88, 256, 0, stream>>>(regcls, boxes, keys);
    rankK         <<<dim3(88, 8), 256, 0, stream>>>(keys, rank);
    scatterK      <<<88, 256, 0, stream>>>(boxes, rank, sboxes);
    nmsMaskK      <<<dim3(375, 4), 256, 0, stream>>>(sboxes, mask);
    nmsScanOutK   <<<1, 64, 0, stream>>>(mask, sboxes, out);
}

// Round 10
// 501.699 us; speedup vs baseline: 1.1671x; 1.1438x over previous
//
#include <hip/hip_runtime.h>

// ---------------------------------------------------------------------------
// RPN forward, MI355X. Only batch element 7 contributes to the output.
// prepK (fused: zero-pad input 512x52x52 + weight->SGPR-layout transpose) ->
// conv3x3 v9 (lane = PIXEL, 2 px/thread, 72 SGPR weights / 144 FMA per cin,
// immediate tap offsets, NO LDS) -> reduce_leaky4 (float4) -> 1x1 heads ->
// decode/score/key -> O(N^2) rank sort -> top-6000 -> NMS bitmask v2
// (lane = j, ballot per word, NO LDS -- replaces 16-way-bank-conflicted
// version; reference's yy2=max bug replicated token-identically) ->
// PAIRED word-serial scan (47 rounds) -> 300x4 boxes. Deterministic fp32:
// per-accumulator FMA chain (cin asc, taps 0..8), CS reduce order, and all
// NMS arithmetic bitwise-identical to prior passing versions.
// ---------------------------------------------------------------------------

#define NPIX 2500      // 50*50
#define NANCH 22500    // 2500*9
#define NKEY 22528     // NANCH padded to 88*256 (sentinel tail)
#define PRE 6000
#define MASKW 94       // ceil(6000/64) usable words
#define MW 96          // storage stride in words
#define JCHUNK 1536    // j-chunk per mask y-block (24 words)
#define CS 8           // cin splits for conv3x3
#define KSLOT 8        // static kept-row load slots per word in scan
#define PW 52          // padded width
#define PSL 2704       // 52*52 padded slice

// ------ fused prep: blocks 0..511 zero-pad x; blocks 512..1087 transpose w -
// wtV[((cin*64 + ocg)*9 + t)*8 + j] = wt[ocg*8+j][cin*9+t]
__global__ __launch_bounds__(256) void prepK(
    const float* __restrict__ x,    // batch-7 base (512,50,50)
    const float* __restrict__ wt,   // (512, 4608)
    float* __restrict__ xpad,       // (512, 52, 52)
    float* __restrict__ wtV)        // (512, 64, 9, 8)
{
    __shared__ float T[64][65];
    const int bx = blockIdx.x;
    if (bx < 512) {
        const int cin = bx;
        const float* src = x + (size_t)cin * NPIX;
        float* dst = xpad + (size_t)cin * PSL;
        for (int i = threadIdx.x; i < PSL; i += 256) {
            const int pr = i / PW;
            const int pc = i - pr * PW;
            float v = 0.f;
            if (pr >= 1 && pr <= 50 && pc >= 1 && pc <= 50)
                v = src[(pr - 1) * 50 + (pc - 1)];
            dst[i] = v;
        }
        return;
    }
    const int idx  = bx - 512;           // 0..575 = 72 x 8
    const int ct0  = (idx % 72) * 64;
    const int ocb  = (idx / 72) * 64;
    const int tid  = threadIdx.x;
    const int cidx = tid & 63;
    const int r4   = tid >> 6;
    #pragma unroll
    for (int i = 0; i < 16; ++i) {
        const int o = r4 + i * 4;
        T[o][cidx] = wt[(size_t)(ocb + o) * 4608 + ct0 + cidx];
    }
    __syncthreads();
    #pragma unroll
    for (int i = 0; i < 16; ++i) {
        const int ctl = ct0 + r4 + i * 4;
        const int cin = ctl / 9;
        const int t   = ctl - cin * 9;
        const int oc  = ocb + cidx;
        wtV[(((size_t)cin * 64 + (oc >> 3)) * 9 + t) * 8 + (oc & 7)] =
            T[cidx][r4 + i * 4];
    }
}

// ---------------- conv 3x3 v9: 2 pixels/thread, padded input, no LDS -------
// grid (64 ocGroups, 5 pxOcts, 8 cin groups) x 256 thr = 10240 waves.
// Per cin: 18 loads at immediate tap offsets + 144 FMA sharing ONE batch of
// 72 SGPR weights. Per-accumulator FMA order bitwise-identical (cin asc,
// taps 0..8).
__global__ __launch_bounds__(256) void conv3x3_v9(
    const float* __restrict__ xpad, // padded batch-7 (512,52,52)
    const float* __restrict__ wtV,  // (512, 64, 9, 8)
    float* __restrict__ part2)      // (CS, 512, 2500)
{
    const int tid  = threadIdx.x;
    const int lane = tid & 63;
    const int wv   = tid >> 6;
    const int ocg  = blockIdx.x;            // 0..63 -> oc = ocg*8 + j
    const int pb   = blockIdx.y * 4 + wv;   // 0..19
    const int cing = blockIdx.z * 64;
    const int px0  = pb * 64 + lane;        // 0..1279 (always valid)
    const int px1  = px0 + 1280;            // 1280..2559
    const bool act1 = (px1 < NPIX);
    const int r0 = px0 / 50, cc0 = px0 - r0 * 50;
    const int px1c = act1 ? px1 : 0;
    const int r1 = px1c / 50, cc1 = px1c - r1 * 50;

    const float* xb0 = xpad + (size_t)cing * PSL + (r0 + 1) * PW + (cc0 + 1);
    const float* xb1 = xpad + (size_t)cing * PSL + (r1 + 1) * PW + (cc1 + 1);

    float acc0[8], acc1[8];
    #pragma unroll
    for (int j = 0; j < 8; ++j) { acc0[j] = 0.f; acc1[j] = 0.f; }

    const float* wbase = wtV + ((size_t)cing * 64 + ocg) * 72;

    for (int cin = 0; cin < 64; ++cin) {
        float v0[9], v1[9];
        const float* xa = xb0 + (size_t)cin * PSL;
        const float* xc = xb1 + (size_t)cin * PSL;
        #pragma unroll
        for (int t = 0; t < 9; ++t) {
            const int dr = t / 3 - 1, dc = t % 3 - 1;
            v0[t] = xa[dr * PW + dc];
            v1[t] = xc[dr * PW + dc];
        }
        const float* wp = wbase + (size_t)cin * 4608;   // 64*72
        #pragma unroll
        for (int j = 0; j < 8; ++j) {
            float a = acc0[j];
            float b = acc1[j];
            #pragma unroll
            for (int t = 0; t < 9; ++t) {
                const float w = wp[t * 8 + j];
                a = fmaf(w, v0[t], a);
                b = fmaf(w, v1[t], b);
            }
            acc0[j] = a;
            acc1[j] = b;
        }
    }

    float* dst0 = part2 + ((size_t)blockIdx.z * 512 + ocg * 8) * NPIX + px0;
    #pragma unroll
    for (int j = 0; j < 8; ++j)
        dst0[(size_t)j * NPIX] = acc0[j];
    if (act1) {
        float* dst1 = part2 + ((size_t)blockIdx.z * 512 + ocg * 8) * NPIX + px1;
        #pragma unroll
        for (int j = 0; j < 8; ++j)
            dst1[(size_t)j * NPIX] = acc1[j];
    }
}

// ------------ reduce partials + bias + leaky (float4 vectorized) -----------
__global__ __launch_bounds__(256) void reduce_leaky4(
    const float* __restrict__ part2, const float* __restrict__ bias,
    float* __restrict__ feat)
{
    const int oc = blockIdx.x;
    const float b = bias[oc];
    float4* dstv = (float4*)(feat + (size_t)oc * NPIX);
    for (int q = threadIdx.x; q < 625; q += 256) {
        float4 s = make_float4(0.f, 0.f, 0.f, 0.f);
        #pragma unroll
        for (int k = 0; k < CS; ++k) {
            const float4 v = *(const float4*)(part2 + ((size_t)k * 512 + oc) * NPIX + q * 4);
            s.x += v.x; s.y += v.y; s.z += v.z; s.w += v.w;
        }
        s.x += b; s.y += b; s.z += b; s.w += b;
        s.x = (s.x >= 0.f) ? s.x : 0.01f * s.x;
        s.y = (s.y >= 0.f) ? s.y : 0.01f * s.y;
        s.z = (s.z >= 0.f) ? s.z : 0.01f * s.z;
        s.w = (s.w >= 0.f) ? s.w : 0.01f * s.w;
        dstv[q] = s;
    }
}

// ---------------- 1x1 heads: 4-wave cin split + LDS tree reduce ------------
__global__ __launch_bounds__(256) void conv1x1_heads(
    const float* __restrict__ feat,
    const float* __restrict__ rw, const float* __restrict__ rb,
    const float* __restrict__ cw, const float* __restrict__ cb,
    float* __restrict__ regcls)   // (54, 2500)
{
    __shared__ float sAcc[3][18][64];
    const int tid  = threadIdx.x;
    const int lane = tid & 63;
    const int wv   = tid >> 6;
    const int pix0 = blockIdx.x * 64 + lane;
    const bool act = (pix0 < NPIX);
    const int pix  = act ? pix0 : (NPIX - 1);
    const int chunk = blockIdx.y;
    const float* wb; const float* bb; int ocbase;
    if (chunk == 0)      { wb = rw;            bb = rb;      ocbase = 0;  }
    else if (chunk == 1) { wb = rw + 18 * 512; bb = rb + 18; ocbase = 18; }
    else                 { wb = cw;            bb = cb;      ocbase = 36; }

    float acc[18];
    #pragma unroll
    for (int k = 0; k < 18; ++k) acc[k] = 0.f;

    const int c0 = wv * 128;
    for (int cin = c0; cin < c0 + 128; ++cin) {
        const float v = feat[(size_t)cin * NPIX + pix];
        #pragma unroll
        for (int k = 0; k < 18; ++k)
            acc[k] = fmaf(wb[k * 512 + cin], v, acc[k]);
    }
    if (wv > 0) {
        #pragma unroll
        for (int k = 0; k < 18; ++k) sAcc[wv - 1][k][lane] = acc[k];
    }
    __syncthreads();
    if (wv == 0 && act) {
        #pragma unroll
        for (int k = 0; k < 18; ++k) {
            float s = acc[k];
            s += sAcc[0][k][lane];
            s += sAcc[1][k][lane];
            s += sAcc[2][k][lane];
            regcls[(size_t)(ocbase + k) * NPIX + pix] = s + bb[k];
        }
    }
}

// ---------------- decode: anchors, softmax score, sortable key -------------
__global__ __launch_bounds__(256) void decodeK(
    const float* __restrict__ regcls,
    float4* __restrict__ boxes,
    unsigned long long* __restrict__ keys)
{
    const int i = blockIdx.x * 256 + threadIdx.x;
    if (i >= NANCH) {
        if (i < NKEY) keys[i] = 0xFFFFFFFFFFFFFFFFull;  // sentinel: > all keys
        return;
    }
    const int pos = i / 9;
    const int a   = i - pos * 9;
    const int hh  = pos / 50;
    const int wwp = pos - hh * 50;
    const int r = a / 3, s = a - r * 3;

    const float base_s[3] = {128.f, 256.f, 512.f};
    const float sq [3] = {0.70710678118654752440f, 1.0f, 1.41421356237309504880f};
    const float sqi[3] = {1.41421356237309504880f, 1.0f, 0.70710678118654752440f};
    const float hs = base_s[s] * sq[r];
    const float ws = base_s[s] * sqi[r];
    const float cx = (float)(hh * 16 + 8);    // cx indexed by h (reference quirk)
    const float cy = (float)(wwp * 16 + 8);
    const float ax = cx - ws * 0.5f;
    const float ay = cy - hs * 0.5f;

    const float pr0 = regcls[(size_t)(a * 4 + 0) * NPIX + pos];
    const float pr1 = regcls[(size_t)(a * 4 + 1) * NPIX + pos];
    const float pr2 = regcls[(size_t)(a * 4 + 2) * NPIX + pos];
    const float pr3 = regcls[(size_t)(a * 4 + 3) * NPIX + pos];
    const float c0  = regcls[(size_t)(36 + a * 2 + 0) * NPIX + pos];
    const float c1  = regcls[(size_t)(36 + a * 2 + 1) * NPIX + pos];

    const float m  = fmaxf(c0, c1);
    const float e0 = expf(c0 - m);
    const float e1 = expf(c1 - m);
    const float score = e1 / (e0 + e1);

    const float t0 = pr0 + ax;
    const float t1 = pr1 + ay;
    const float hi = 799.0f;
    const float rx1 = fminf(fmaxf(t0, 0.f), hi);
    const float ry1 = fminf(fmaxf(t1, 0.f), hi);
    const float rx2 = fminf(fmaxf((t0 + pr2) + ws, 0.f), hi);
    const float ry2 = fminf(fmaxf((t1 + pr3) + hs, 0.f), hi);
    const float bw = pr2 + ws;
    const float bh = pr3 + hs;
    const bool valid = (bw >= 16.f) && (bh >= 16.f);
    const float sc = valid ? score : -__builtin_inff();

    unsigned u = __float_as_uint(sc);
    u = (u & 0x80000000u) ? ~u : (u | 0x80000000u);  // monotone ascending map
    const unsigned k32 = ~u;                          // descending score
    keys[i]  = ((unsigned long long)k32 << 32) | (unsigned)i;  // tie: asc index
    boxes[i] = make_float4(rx1, ry1, rx2, ry2);
}

// ---------------- O(N^2) rank (stable argsort position) --------------------
__global__ __launch_bounds__(256) void rankK(
    const unsigned long long* __restrict__ keys, int* __restrict__ rank)
{
    const int i = blockIdx.x * 256 + threadIdx.x;
    const unsigned long long my = (i < NANCH) ? keys[i] : 0ull;
    const unsigned long long* kj = keys + blockIdx.y * 2816;
    int cnt = 0;
    for (int t = 0; t < 2816; t += 8) {
        #pragma unroll
        for (int q = 0; q < 8; ++q)
            cnt += (kj[t + q] < my) ? 1 : 0;
    }
    if (i < NANCH) atomicAdd(&rank[i], cnt);
}

__global__ __launch_bounds__(256) void scatterK(
    const float4* __restrict__ boxes, const int* __restrict__ rank,
    float4* __restrict__ sboxes)
{
    const int i = blockIdx.x * 256 + threadIdx.x;
    if (i < NANCH) {
        const int r = rank[i];
        if (r < PRE) sboxes[r] = boxes[i];
    }
}

// ------------- NMS suppression bitmask v2: lane = j, ballot, NO LDS --------
// grid (375, 4) x 256 thr. wave wv handles i in [bx*16+wv*4, +4); lane owns
// j = jbase + w*64 + lane. Per (i,w): one __ballot(j>i && j<PRE && ov>0.7)
// produces the 64-bit word directly (bit u == lane u == candidate j).
// IoU arithmetic is token-identical to the prior LDS version (including the
// replicated yy2=max reference bug and the precise division) -> identical
// mask bits. Replaces a 16-way-bank-conflicted LDS gather (lanes differing
// only in w hit the same bank) with coalesced float4 global loads of the
// L2-resident 96 KB sboxes array.
__global__ __launch_bounds__(256) void nmsMaskK(
    const float4* __restrict__ sb, unsigned long long* __restrict__ mask)
{
    const int tid  = threadIdx.x;
    const int lane = tid & 63;
    const int wv   = tid >> 6;
    const int i0   = blockIdx.x * 16 + wv * 4;   // 4 i-rows per wave
    const int jbase = blockIdx.y * JCHUNK;

    float ix1[4], iy1[4], ix2[4], iy2[4], iar[4];
    #pragma unroll
    for (int ii = 0; ii < 4; ++ii) {
        const float4 b = sb[i0 + ii];
        ix1[ii] = b.x; iy1[ii] = b.y; ix2[ii] = b.z; iy2[ii] = b.w;
        iar[ii] = (b.z - b.x + 1.f) * (b.w - b.y + 1.f);
    }

    for (int w = 0; w < 24; ++w) {
        const int j  = jbase + w * 64 + lane;
        const int jc = (j < PRE) ? j : 0;            // clamp OOB load
        const float4 bj = sb[jc];
        const float jar = (bj.z - bj.x + 1.f) * (bj.w - bj.y + 1.f);
        #pragma unroll
        for (int ii = 0; ii < 4; ++ii) {
            const int i = i0 + ii;
            const float xx1 = fmaxf(ix1[ii], bj.x);
            const float yy1 = fmaxf(iy1[ii], bj.y);
            const float xx2 = fminf(ix2[ii], bj.z);
            const float yy2 = fmaxf(iy2[ii], bj.w);   // reference bug: max
            const float wvv = fmaxf(0.f, xx2 - xx1 + 1.f);
            const float hvv = fmaxf(0.f, yy2 - yy1 + 1.f);
            const float inter = wvv * hvv;
            const float ov = inter / ((iar[ii] + jar) - inter);  // precise div
            const bool pred = (j > i) && (j < PRE) && (ov > 0.7f);
            const unsigned long long bits = __ballot(pred);
            if (lane == 0)
                mask[(size_t)i * MW + blockIdx.y * 24 + w] = bits;
        }
    }
}

// ------------- PAIRED word-serial NMS scan + output (single wave) ----------
// Processes TWO 64-candidate blocks (g0=2p, g1=2p+1) per round using three
// preloaded diagonal words: d00=row(g0)[g0], d01=row(g0)[g1] (superdiag),
// d11=row(g1)[g1]. Keeps drain g0 first then g1 (index order preserved;
// g1 keeps cannot suppress g0). Keep set identical to the unpaired scan.
__global__ __launch_bounds__(64) void nmsScanOutK(
    const unsigned long long* __restrict__ mask,
    const float4* __restrict__ sb,
    float* __restrict__ out)
{
    __shared__ int sKept[300];
    __shared__ unsigned long long sKeepW[MASKW];
    const int lane = threadIdx.x;

    unsigned long long rem0 = 0ull, rem1 = 0ull;   // lane l: words l, 64+l
    int cnt = 0;
    int done = 0;

    // preload pair 0 diagonals
    unsigned long long d00 = mask[(size_t)lane * MW + 0];
    unsigned long long d01 = mask[(size_t)lane * MW + 1];
    unsigned long long d11 = mask[(size_t)(64 + lane) * MW + 1];

    for (int p = 0; p < 47 && !done; ++p) {
        const int g0 = 2 * p, g1 = 2 * p + 1;

        // prefetch next pair's three diagonal words (overlap with this round)
        unsigned long long n00 = 0ull, n01 = 0ull, n11 = 0ull;
        if (p + 1 < 47) {
            const int h0 = g0 + 2, h1 = g0 + 3;
            const int ra = h0 * 64 + lane;
            const int rb = h1 * 64 + lane;
            n00 = mask[(size_t)ra * MW + h0];
            n01 = mask[(size_t)ra * MW + h1];
            if (rb < PRE) n11 = mask[(size_t)rb * MW + h1];
        }

        // broadcast current suppression words g0, g1 from rem
        unsigned long long cur0, cur1;
        {
            unsigned lo, hi;
            if (g0 < 64) {
                lo = __builtin_amdgcn_readlane((unsigned)rem0, g0);
                hi = __builtin_amdgcn_readlane((unsigned)(rem0 >> 32), g0);
            } else {
                lo = __builtin_amdgcn_readlane((unsigned)rem1, g0 - 64);
                hi = __builtin_amdgcn_readlane((unsigned)(rem1 >> 32), g0 - 64);
            }
            cur0 = ((unsigned long long)hi << 32) | lo;
            if (g1 < 64) {
                lo = __builtin_amdgcn_readlane((unsigned)rem0, g1);
                hi = __builtin_amdgcn_readlane((unsigned)(rem0 >> 32), g1);
            } else {
                lo = __builtin_amdgcn_readlane((unsigned)rem1, g1 - 64);
                hi = __builtin_amdgcn_readlane((unsigned)(rem1 >> 32), g1 - 64);
            }
            cur1 = ((unsigned long long)hi << 32) | lo;
        }
        const unsigned long long valid0 = ~0ull;    // g0 <= 92: always full
        const unsigned long long valid1 =
            (g1 == MASKW - 1) ? 0x0000FFFFFFFFFFFFull : ~0ull;  // 48 tail bits

        // ---- phase A: drain block g0 keeps (pure ALU) ----
        unsigned long long kb0 = 0ull, kb1 = 0ull;
        for (;;) {
            const unsigned long long nd = (~cur0) & valid0;
            if (!nd) break;
            const int b = __builtin_ctzll(nd);
            if (lane == 0 && cnt < 300) sKept[cnt] = g0 * 64 + b;
            ++cnt;
            kb0 |= (1ull << b);
            if (cnt >= 300) { done = 1; break; }
            const unsigned al = __builtin_amdgcn_readlane((unsigned)d00, b);
            const unsigned ah = __builtin_amdgcn_readlane((unsigned)(d00 >> 32), b);
            const unsigned bl = __builtin_amdgcn_readlane((unsigned)d01, b);
            const unsigned bh = __builtin_amdgcn_readlane((unsigned)(d01 >> 32), b);
            cur0 |= (1ull << b) | (((unsigned long long)ah << 32) | al);
            cur1 |= (((unsigned long long)bh << 32) | bl);
        }
        // ---- phase B: drain block g1 keeps ----
        if (!done) {
            for (;;) {
                const unsigned long long nd = (~cur1) & valid1;
                if (!nd) break;
                const int b = __builtin_ctzll(nd);
                if (lane == 0 && cnt < 300) sKept[cnt] = g1 * 64 + b;
                ++cnt;
                kb1 |= (1ull << b);
                if (cnt >= 300) { done = 1; break; }
                const unsigned cl = __builtin_amdgcn_readlane((unsigned)d11, b);
                const unsigned ch = __builtin_amdgcn_readlane((unsigned)(d11 >> 32), b);
                cur1 |= (1ull << b) | (((unsigned long long)ch << 32) | cl);
            }
        }
        if (lane == 0) { sKeepW[g0] = kb0; sKeepW[g1] = kb1; }

        // ---- batched kept-row loads for BOTH blocks, one rem update ----
        if (!done && (kb0 | kb1)) {
            unsigned long long a0 = 0ull, a1 = 0ull;
            {
                int kbit[KSLOT];
                unsigned long long t = kb0;
                #pragma unroll
                for (int s = 0; s < KSLOT; ++s) {
                    kbit[s] = t ? __builtin_ctzll(t) : 64;
                    t &= t - 1;
                }
                #pragma unroll
                for (int s = 0; s < KSLOT; ++s) {
                    if (kbit[s] < 64) {            // wave-uniform branch
                        const unsigned long long* pr =
                            mask + (size_t)(g0 * 64 + kbit[s]) * MW;
                        a0 |= pr[lane];
                        a1 |= (lane < MASKW - 64) ? pr[64 + lane] : 0ull;
                    }
                }
                while (t) {                         // >KSLOT overflow (rare)
                    const int b = __builtin_ctzll(t); t &= t - 1;
                    const unsigned long long* pr =
                        mask + (size_t)(g0 * 64 + b) * MW;
                    a0 |= pr[lane];
                    a1 |= (lane < MASKW - 64) ? pr[64 + lane] : 0ull;
                }
            }
            {
                int kbit[KSLOT];
                unsigned long long t = kb1;
                #pragma unroll
                for (int s = 0; s < KSLOT; ++s) {
                    kbit[s] = t ? __builtin_ctzll(t) : 64;
                    t &= t - 1;
                }
                #pragma unroll
                for (int s = 0; s < KSLOT; ++s) {
                    if (kbit[s] < 64) {            // wave-uniform branch
                        const unsigned long long* pr =
                            mask + (size_t)(g1 * 64 + kbit[s]) * MW;
                        a0 |= pr[lane];
                        a1 |= (lane < MASKW - 64) ? pr[64 + lane] : 0ull;
                    }
                }
                while (t) {                         // >KSLOT overflow (rare)
                    const int b = __builtin_ctzll(t); t &= t - 1;
                    const unsigned long long* pr =
                        mask + (size_t)(g1 * 64 + b) * MW;
                    a0 |= pr[lane];
                    a1 |= (lane < MASKW - 64) ? pr[64 + lane] : 0ull;
                }
            }
            rem0 |= a0;
            rem1 |= a1;
        }
        d00 = n00; d01 = n01; d11 = n11;
    }

    __syncthreads();

    if (cnt < 300) {                                 // filler: unkept, asc index
        int c = cnt;
        for (int g = 0; g < MASKW && c < 300; ++g) {
            const unsigned long long valid =
                (g == MASKW - 1) ? 0x0000FFFFFFFFFFFFull : ~0ull;
            unsigned long long u = (~sKeepW[g]) & valid;
            while (u && c < 300) {
                const int b = __builtin_ctzll(u); u &= u - 1;
                if (lane == 0) sKept[c] = g * 64 + b;
                ++c;
            }
        }
    }
    __syncthreads();

    for (int s = lane; s < 300; s += 64) {
        const float4 b = sb[sKept[s]];
        out[s * 4 + 0] = b.x;
        out[s * 4 + 1] = b.y;
        out[s * 4 + 2] = b.z - b.x + 1.0f;
        out[s * 4 + 3] = b.w - b.y + 1.0f;
    }
}

// ---------------------------------------------------------------------------
extern "C" void kernel_launch(void* const* d_in, const int* in_sizes, int n_in,
                              void* d_out, int out_size, void* d_ws, size_t ws_size,
                              hipStream_t stream)
{
    (void)in_sizes; (void)n_in; (void)out_size; (void)ws_size;
    const float* x   = (const float*)d_in[0] + (size_t)7 * 512 * NPIX; // batch 7
    const float* cw3 = (const float*)d_in[1];
    const float* cb3 = (const float*)d_in[2];
    const float* rw  = (const float*)d_in[3];
    const float* rb  = (const float*)d_in[4];
    const float* clw = (const float*)d_in[5];
    const float* clb = (const float*)d_in[6];
    float* out = (float*)d_out;

    char* p = (char*)d_ws;
    auto alloc = [&](size_t n) { char* r = p; p += (n + 255) & ~(size_t)255; return r; };
    float*  part2  = (float*)alloc((size_t)CS * 512 * NPIX * 4);  // 41 MB
    float*  wtV    = (float*)alloc((size_t)4608 * 512 * 4);       // 9.4 MB
    float*  xpad   = (float*)alloc((size_t)512 * PSL * 4);        // 5.5 MB
    float*  feat   = (float*)alloc((size_t)512 * NPIX * 4);       // 5.12 MB
    float*  regcls = (float*)alloc((size_t)54 * NPIX * 4);        // 0.54 MB
    float4* boxes  = (float4*)alloc((size_t)NANCH * 16);          // 0.36 MB
    unsigned long long* keys = (unsigned long long*)alloc((size_t)NKEY * 8);
    int*    rank   = (int*)alloc((size_t)NANCH * 4);
    float4* sboxes = (float4*)alloc((size_t)PRE * 16);
    unsigned long long* mask = (unsigned long long*)alloc((size_t)PRE * MW * 8); // 4.6 MB

    hipMemsetAsync(rank, 0, (size_t)NANCH * 4, stream);
    prepK         <<<1088, 256, 0, stream>>>(x, cw3, xpad, wtV);
    conv3x3_v9    <<<dim3(64, 5, CS), 256, 0, stream>>>(xpad, wtV, part2);
    reduce_leaky4 <<<512, 256, 0, stream>>>(part2, cb3, feat);
    conv1x1_heads <<<dim3(40, 3), 256, 0, stream>>>(feat, rw, rb, clw, clb, regcls);
    decodeK       <<<88, 256, 0, stream>>>(regcls, boxes, keys);
    rankK         <<<dim3(88, 8), 256, 0, stream>>>(keys, rank);
    scatterK      <<<88, 256, 0, stream>>>(boxes, rank, sboxes);
    nmsMaskK      <<<dim3(375, 4), 256, 0, stream>>>(sboxes, mask);
    nmsScanOutK   <<<1, 64, 0, stream>>>(mask, sboxes, out);
}

// Round 11
// 468.775 us; speedup vs baseline: 1.2490x; 1.0702x over previous
//
#include <hip/hip_runtime.h>

// ---------------------------------------------------------------------------
// RPN forward, MI355X. Only batch element 7 contributes to the output.
// prepK (fused: zero-pad input 512x52x52 + weight->SGPR-layout transpose) ->
// conv3x3 v11 (lane = PIXEL, 2 px/thread, 72 SGPR weights / 144 FMA per cin,
// A/B register double-buffer: x-taps prefetched one full cin ahead,
// immediate tap offsets, NO LDS) -> reduce_leaky4 (float4) -> 1x1 heads
// (k-split x3 for occupancy) -> decode/score/key (+rank zeroing) ->
// O(N^2) rank sort -> top-6000 -> NMS bitmask v2 (lane=j, ballot, NO LDS;
// reference's yy2=max bug replicated token-identically) -> PAIRED
// word-serial scan (47 rounds) -> 300x4 boxes. Deterministic fp32:
// per-accumulator FMA chain (cin asc, taps 0..8), CS reduce order, heads
// sum order, and all NMS arithmetic bitwise-identical to prior versions.
// ---------------------------------------------------------------------------

#define NPIX 2500      // 50*50
#define NANCH 22500    // 2500*9
#define NKEY 22528     // NANCH padded to 88*256 (sentinel tail)
#define PRE 6000
#define MASKW 94       // ceil(6000/64) usable words
#define MW 96          // storage stride in words
#define JCHUNK 1536    // j-chunk per mask y-block (24 words)
#define CS 8           // cin splits for conv3x3
#define KSLOT 8        // static kept-row load slots per word in scan
#define PW 52          // padded width
#define PSL 2704       // 52*52 padded slice

// ------ fused prep: blocks 0..511 zero-pad x; blocks 512..1087 transpose w -
// wtV[((cin*64 + ocg)*9 + t)*8 + j] = wt[ocg*8+j][cin*9+t]
__global__ __launch_bounds__(256) void prepK(
    const float* __restrict__ x,    // batch-7 base (512,50,50)
    const float* __restrict__ wt,   // (512, 4608)
    float* __restrict__ xpad,       // (512, 52, 52)
    float* __restrict__ wtV)        // (512, 64, 9, 8)
{
    __shared__ float T[64][65];
    const int bx = blockIdx.x;
    if (bx < 512) {
        const int cin = bx;
        const float* src = x + (size_t)cin * NPIX;
        float* dst = xpad + (size_t)cin * PSL;
        for (int i = threadIdx.x; i < PSL; i += 256) {
            const int pr = i / PW;
            const int pc = i - pr * PW;
            float v = 0.f;
            if (pr >= 1 && pr <= 50 && pc >= 1 && pc <= 50)
                v = src[(pr - 1) * 50 + (pc - 1)];
            dst[i] = v;
        }
        return;
    }
    const int idx  = bx - 512;           // 0..575 = 72 x 8
    const int ct0  = (idx % 72) * 64;
    const int ocb  = (idx / 72) * 64;
    const int tid  = threadIdx.x;
    const int cidx = tid & 63;
    const int r4   = tid >> 6;
    #pragma unroll
    for (int i = 0; i < 16; ++i) {
        const int o = r4 + i * 4;
        T[o][cidx] = wt[(size_t)(ocb + o) * 4608 + ct0 + cidx];
    }
    __syncthreads();
    #pragma unroll
    for (int i = 0; i < 16; ++i) {
        const int ctl = ct0 + r4 + i * 4;
        const int cin = ctl / 9;
        const int t   = ctl - cin * 9;
        const int oc  = ocb + cidx;
        wtV[(((size_t)cin * 64 + (oc >> 3)) * 9 + t) * 8 + (oc & 7)] =
            T[cidx][r4 + i * 4];
    }
}

// ------- conv 3x3 v11: 2 px/thread, A/B x-prefetch, padded input, no LDS ---
// grid (64 ocGroups, 5 pxOcts, 8 cin groups) x 256 thr = 10240 waves.
// Per cin: 18 loads at immediate tap offsets prefetched ONE FULL cin (~288
// FMA cycles) ahead via A/B register buffers + 144 FMA sharing ONE batch of
// 72 SGPR weights. Per-accumulator FMA order bitwise-identical (cin asc,
// taps 0..8): even cins consume buffer A, odd consume B, same chains.
__global__ __launch_bounds__(256) void conv3x3_v11(
    const float* __restrict__ xpad, // padded batch-7 (512,52,52)
    const float* __restrict__ wtV,  // (512, 64, 9, 8)
    float* __restrict__ part2)      // (CS, 512, 2500)
{
    const int tid  = threadIdx.x;
    const int lane = tid & 63;
    const int wv   = tid >> 6;
    const int ocg  = blockIdx.x;            // 0..63 -> oc = ocg*8 + j
    const int pb   = blockIdx.y * 4 + wv;   // 0..19
    const int cing = blockIdx.z * 64;
    const int px0  = pb * 64 + lane;        // 0..1279 (always valid)
    const int px1  = px0 + 1280;            // 1280..2559
    const bool act1 = (px1 < NPIX);
    const int r0 = px0 / 50, cc0 = px0 - r0 * 50;
    const int px1c = act1 ? px1 : 0;
    const int r1 = px1c / 50, cc1 = px1c - r1 * 50;

    const float* xb0 = xpad + (size_t)cing * PSL + (r0 + 1) * PW + (cc0 + 1);
    const float* xb1 = xpad + (size_t)cing * PSL + (r1 + 1) * PW + (cc1 + 1);

    float acc0[8], acc1[8];
    #pragma unroll
    for (int j = 0; j < 8; ++j) { acc0[j] = 0.f; acc1[j] = 0.f; }

    const float* wbase = wtV + ((size_t)cing * 64 + ocg) * 72;

    // A/B window double-buffer
    float vA0[9], vA1[9], vB0[9], vB1[9];
    #pragma unroll
    for (int t = 0; t < 9; ++t) {           // prologue: load cin=0 into A
        const int dr = t / 3 - 1, dc = t % 3 - 1;
        vA0[t] = xb0[dr * PW + dc];
        vA1[t] = xb1[dr * PW + dc];
    }

    for (int cin = 0; cin < 64; cin += 2) {
        // issue B loads for cin+1 (land under the A FMA block)
        {
            const float* xa = xb0 + (size_t)(cin + 1) * PSL;
            const float* xc = xb1 + (size_t)(cin + 1) * PSL;
            #pragma unroll
            for (int t = 0; t < 9; ++t) {
                const int dr = t / 3 - 1, dc = t % 3 - 1;
                vB0[t] = xa[dr * PW + dc];
                vB1[t] = xc[dr * PW + dc];
            }
        }
        {   // FMA with A = values(cin), weights wp(cin)
            const float* wp = wbase + (size_t)cin * 4608;   // 64*72
            #pragma unroll
            for (int j = 0; j < 8; ++j) {
                float a = acc0[j];
                float b = acc1[j];
                #pragma unroll
                for (int t = 0; t < 9; ++t) {
                    const float w = wp[t * 8 + j];
                    a = fmaf(w, vA0[t], a);
                    b = fmaf(w, vA1[t], b);
                }
                acc0[j] = a;
                acc1[j] = b;
            }
        }
        // issue A loads for cin+2 (land under the B FMA block)
        if (cin + 2 < 64) {
            const float* xa = xb0 + (size_t)(cin + 2) * PSL;
            const float* xc = xb1 + (size_t)(cin + 2) * PSL;
            #pragma unroll
            for (int t = 0; t < 9; ++t) {
                const int dr = t / 3 - 1, dc = t % 3 - 1;
                vA0[t] = xa[dr * PW + dc];
                vA1[t] = xc[dr * PW + dc];
            }
        }
        {   // FMA with B = values(cin+1), weights wp(cin+1)
            const float* wp = wbase + (size_t)(cin + 1) * 4608;
            #pragma unroll
            for (int j = 0; j < 8; ++j) {
                float a = acc0[j];
                float b = acc1[j];
                #pragma unroll
                for (int t = 0; t < 9; ++t) {
                    const float w = wp[t * 8 + j];
                    a = fmaf(w, vB0[t], a);
                    b = fmaf(w, vB1[t], b);
                }
                acc0[j] = a;
                acc1[j] = b;
            }
        }
    }

    float* dst0 = part2 + ((size_t)blockIdx.z * 512 + ocg * 8) * NPIX + px0;
    #pragma unroll
    for (int j = 0; j < 8; ++j)
        dst0[(size_t)j * NPIX] = acc0[j];
    if (act1) {
        float* dst1 = part2 + ((size_t)blockIdx.z * 512 + ocg * 8) * NPIX + px1;
        #pragma unroll
        for (int j = 0; j < 8; ++j)
            dst1[(size_t)j * NPIX] = acc1[j];
    }
}

// ------------ reduce partials + bias + leaky (float4 vectorized) -----------
__global__ __launch_bounds__(256) void reduce_leaky4(
    const float* __restrict__ part2, const float* __restrict__ bias,
    float* __restrict__ feat)
{
    const int oc = blockIdx.x;
    const float b = bias[oc];
    float4* dstv = (float4*)(feat + (size_t)oc * NPIX);
    for (int q = threadIdx.x; q < 625; q += 256) {
        float4 s = make_float4(0.f, 0.f, 0.f, 0.f);
        #pragma unroll
        for (int k = 0; k < CS; ++k) {
            const float4 v = *(const float4*)(part2 + ((size_t)k * 512 + oc) * NPIX + q * 4);
            s.x += v.x; s.y += v.y; s.z += v.z; s.w += v.w;
        }
        s.x += b; s.y += b; s.z += b; s.w += b;
        s.x = (s.x >= 0.f) ? s.x : 0.01f * s.x;
        s.y = (s.y >= 0.f) ? s.y : 0.01f * s.y;
        s.z = (s.z >= 0.f) ? s.z : 0.01f * s.z;
        s.w = (s.w >= 0.f) ? s.w : 0.01f * s.w;
        dstv[q] = s;
    }
}

// -------- 1x1 heads: 4-wave cin split + LDS tree reduce, k-split x3 --------
// grid (40, 3, 3): z = k-sixth (6 of 18 outputs) -> 360 blocks (3x waves vs
// 120). Outputs are independent across k: per-output cin-sum chain and the
// w0+s0+s1+s2+bias order are unchanged (bitwise).
__global__ __launch_bounds__(256) void conv1x1_heads(
    const float* __restrict__ feat,
    const float* __restrict__ rw, const float* __restrict__ rb,
    const float* __restrict__ cw, const float* __restrict__ cb,
    float* __restrict__ regcls)   // (54, 2500)
{
    __shared__ float sAcc[3][6][64];
    const int tid  = threadIdx.x;
    const int lane = tid & 63;
    const int wv   = tid >> 6;
    const int pix0 = blockIdx.x * 64 + lane;
    const bool act = (pix0 < NPIX);
    const int pix  = act ? pix0 : (NPIX - 1);
    const int chunk = blockIdx.y;
    const int k0    = blockIdx.z * 6;            // 0, 6, 12
    const float* wb; const float* bb; int ocbase;
    if (chunk == 0)      { wb = rw;            bb = rb;      ocbase = 0;  }
    else if (chunk == 1) { wb = rw + 18 * 512; bb = rb + 18; ocbase = 18; }
    else                 { wb = cw;            bb = cb;      ocbase = 36; }

    float acc[6];
    #pragma unroll
    for (int k = 0; k < 6; ++k) acc[k] = 0.f;

    const int c0 = wv * 128;
    for (int cin = c0; cin < c0 + 128; ++cin) {
        const float v = feat[(size_t)cin * NPIX + pix];
        #pragma unroll
        for (int k = 0; k < 6; ++k)
            acc[k] = fmaf(wb[(k0 + k) * 512 + cin], v, acc[k]);
    }
    if (wv > 0) {
        #pragma unroll
        for (int k = 0; k < 6; ++k) sAcc[wv - 1][k][lane] = acc[k];
    }
    __syncthreads();
    if (wv == 0 && act) {
        #pragma unroll
        for (int k = 0; k < 6; ++k) {
            float s = acc[k];
            s += sAcc[0][k][lane];
            s += sAcc[1][k][lane];
            s += sAcc[2][k][lane];
            regcls[(size_t)(ocbase + k0 + k) * NPIX + pix] = s + bb[k0 + k];
        }
    }
}

// ------- decode: anchors, softmax score, sortable key (+ rank zeroing) -----
__global__ __launch_bounds__(256) void decodeK(
    const float* __restrict__ regcls,
    float4* __restrict__ boxes,
    unsigned long long* __restrict__ keys,
    int* __restrict__ rank)
{
    const int i = blockIdx.x * 256 + threadIdx.x;
    if (i < NANCH) rank[i] = 0;               // replaces hipMemsetAsync
    if (i >= NANCH) {
        if (i < NKEY) keys[i] = 0xFFFFFFFFFFFFFFFFull;  // sentinel: > all keys
        return;
    }
    const int pos = i / 9;
    const int a   = i - pos * 9;
    const int hh  = pos / 50;
    const int wwp = pos - hh * 50;
    const int r = a / 3, s = a - r * 3;

    const float base_s[3] = {128.f, 256.f, 512.f};
    const float sq [3] = {0.70710678118654752440f, 1.0f, 1.41421356237309504880f};
    const float sqi[3] = {1.41421356237309504880f, 1.0f, 0.70710678118654752440f};
    const float hs = base_s[s] * sq[r];
    const float ws = base_s[s] * sqi[r];
    const float cx = (float)(hh * 16 + 8);    // cx indexed by h (reference quirk)
    const float cy = (float)(wwp * 16 + 8);
    const float ax = cx - ws * 0.5f;
    const float ay = cy - hs * 0.5f;

    const float pr0 = regcls[(size_t)(a * 4 + 0) * NPIX + pos];
    const float pr1 = regcls[(size_t)(a * 4 + 1) * NPIX + pos];
    const float pr2 = regcls[(size_t)(a * 4 + 2) * NPIX + pos];
    const float pr3 = regcls[(size_t)(a * 4 + 3) * NPIX + pos];
    const float c0  = regcls[(size_t)(36 + a * 2 + 0) * NPIX + pos];
    const float c1  = regcls[(size_t)(36 + a * 2 + 1) * NPIX + pos];

    const float m  = fmaxf(c0, c1);
    const float e0 = expf(c0 - m);
    const float e1 = expf(c1 - m);
    const float score = e1 / (e0 + e1);

    const float t0 = pr0 + ax;
    const float t1 = pr1 + ay;
    const float hi = 799.0f;
    const float rx1 = fminf(fmaxf(t0, 0.f), hi);
    const float ry1 = fminf(fmaxf(t1, 0.f), hi);
    const float rx2 = fminf(fmaxf((t0 + pr2) + ws, 0.f), hi);
    const float ry2 = fminf(fmaxf((t1 + pr3) + hs, 0.f), hi);
    const float bw = pr2 + ws;
    const float bh = pr3 + hs;
    const bool valid = (bw >= 16.f) && (bh >= 16.f);
    const float sc = valid ? score : -__builtin_inff();

    unsigned u = __float_as_uint(sc);
    u = (u & 0x80000000u) ? ~u : (u | 0x80000000u);  // monotone ascending map
    const unsigned k32 = ~u;                          // descending score
    keys[i]  = ((unsigned long long)k32 << 32) | (unsigned)i;  // tie: asc index
    boxes[i] = make_float4(rx1, ry1, rx2, ry2);
}

// ---------------- O(N^2) rank (stable argsort position) --------------------
__global__ __launch_bounds__(256) void rankK(
    const unsigned long long* __restrict__ keys, int* __restrict__ rank)
{
    const int i = blockIdx.x * 256 + threadIdx.x;
    const unsigned long long my = (i < NANCH) ? keys[i] : 0ull;
    const unsigned long long* kj = keys + blockIdx.y * 2816;
    int cnt = 0;
    for (int t = 0; t < 2816; t += 8) {
        #pragma unroll
        for (int q = 0; q < 8; ++q)
            cnt += (kj[t + q] < my) ? 1 : 0;
    }
    if (i < NANCH) atomicAdd(&rank[i], cnt);
}

__global__ __launch_bounds__(256) void scatterK(
    const float4* __restrict__ boxes, const int* __restrict__ rank,
    float4* __restrict__ sboxes)
{
    const int i = blockIdx.x * 256 + threadIdx.x;
    if (i < NANCH) {
        const int r = rank[i];
        if (r < PRE) sboxes[r] = boxes[i];
    }
}

// ------------- NMS suppression bitmask v2: lane = j, ballot, NO LDS --------
__global__ __launch_bounds__(256) void nmsMaskK(
    const float4* __restrict__ sb, unsigned long long* __restrict__ mask)
{
    const int tid  = threadIdx.x;
    const int lane = tid & 63;
    const int wv   = tid >> 6;
    const int i0   = blockIdx.x * 16 + wv * 4;   // 4 i-rows per wave
    const int jbase = blockIdx.y * JCHUNK;

    float ix1[4], iy1[4], ix2[4], iy2[4], iar[4];
    #pragma unroll
    for (int ii = 0; ii < 4; ++ii) {
        const float4 b = sb[i0 + ii];
        ix1[ii] = b.x; iy1[ii] = b.y; ix2[ii] = b.z; iy2[ii] = b.w;
        iar[ii] = (b.z - b.x + 1.f) * (b.w - b.y + 1.f);
    }

    for (int w = 0; w < 24; ++w) {
        const int j  = jbase + w * 64 + lane;
        const int jc = (j < PRE) ? j : 0;            // clamp OOB load
        const float4 bj = sb[jc];
        const float jar = (bj.z - bj.x + 1.f) * (bj.w - bj.y + 1.f);
        #pragma unroll
        for (int ii = 0; ii < 4; ++ii) {
            const int i = i0 + ii;
            const float xx1 = fmaxf(ix1[ii], bj.x);
            const float yy1 = fmaxf(iy1[ii], bj.y);
            const float xx2 = fminf(ix2[ii], bj.z);
            const float yy2 = fmaxf(iy2[ii], bj.w);   // reference bug: max
            const float wvv = fmaxf(0.f, xx2 - xx1 + 1.f);
            const float hvv = fmaxf(0.f, yy2 - yy1 + 1.f);
            const float inter = wvv * hvv;
            const float ov = inter / ((iar[ii] + jar) - inter);  // precise div
            const bool pred = (j > i) && (j < PRE) && (ov > 0.7f);
            const unsigned long long bits = __ballot(pred);
            if (lane == 0)
                mask[(size_t)i * MW + blockIdx.y * 24 + w] = bits;
        }
    }
}

// ------------- PAIRED word-serial NMS scan + output (single wave) ----------
__global__ __launch_bounds__(64) void nmsScanOutK(
    const unsigned long long* __restrict__ mask,
    const float4* __restrict__ sb,
    float* __restrict__ out)
{
    __shared__ int sKept[300];
    __shared__ unsigned long long sKeepW[MASKW];
    const int lane = threadIdx.x;

    unsigned long long rem0 = 0ull, rem1 = 0ull;   // lane l: words l, 64+l
    int cnt = 0;
    int done = 0;

    // preload pair 0 diagonals
    unsigned long long d00 = mask[(size_t)lane * MW + 0];
    unsigned long long d01 = mask[(size_t)lane * MW + 1];
    unsigned long long d11 = mask[(size_t)(64 + lane) * MW + 1];

    for (int p = 0; p < 47 && !done; ++p) {
        const int g0 = 2 * p, g1 = 2 * p + 1;

        // prefetch next pair's three diagonal words (overlap with this round)
        unsigned long long n00 = 0ull, n01 = 0ull, n11 = 0ull;
        if (p + 1 < 47) {
            const int h0 = g0 + 2, h1 = g0 + 3;
            const int ra = h0 * 64 + lane;
            const int rb = h1 * 64 + lane;
            n00 = mask[(size_t)ra * MW + h0];
            n01 = mask[(size_t)ra * MW + h1];
            if (rb < PRE) n11 = mask[(size_t)rb * MW + h1];
        }

        // broadcast current suppression words g0, g1 from rem
        unsigned long long cur0, cur1;
        {
            unsigned lo, hi;
            if (g0 < 64) {
                lo = __builtin_amdgcn_readlane((unsigned)rem0, g0);
                hi = __builtin_amdgcn_readlane((unsigned)(rem0 >> 32), g0);
            } else {
                lo = __builtin_amdgcn_readlane((unsigned)rem1, g0 - 64);
                hi = __builtin_amdgcn_readlane((unsigned)(rem1 >> 32), g0 - 64);
            }
            cur0 = ((unsigned long long)hi << 32) | lo;
            if (g1 < 64) {
                lo = __builtin_amdgcn_readlane((unsigned)rem0, g1);
                hi = __builtin_amdgcn_readlane((unsigned)(rem0 >> 32), g1);
            } else {
                lo = __builtin_amdgcn_readlane((unsigned)rem1, g1 - 64);
                hi = __builtin_amdgcn_readlane((unsigned)(rem1 >> 32), g1 - 64);
            }
            cur1 = ((unsigned long long)hi << 32) | lo;
        }
        const unsigned long long valid0 = ~0ull;    // g0 <= 92: always full
        const unsigned long long valid1 =
            (g1 == MASKW - 1) ? 0x0000FFFFFFFFFFFFull : ~0ull;  // 48 tail bits

        // ---- phase A: drain block g0 keeps (pure ALU) ----
        unsigned long long kb0 = 0ull, kb1 = 0ull;
        for (;;) {
            const unsigned long long nd = (~cur0) & valid0;
            if (!nd) break;
            const int b = __builtin_ctzll(nd);
            if (lane == 0 && cnt < 300) sKept[cnt] = g0 * 64 + b;
            ++cnt;
            kb0 |= (1ull << b);
            if (cnt >= 300) { done = 1; break; }
            const unsigned al = __builtin_amdgcn_readlane((unsigned)d00, b);
            const unsigned ah = __builtin_amdgcn_readlane((unsigned)(d00 >> 32), b);
            const unsigned bl = __builtin_amdgcn_readlane((unsigned)d01, b);
            const unsigned bh = __builtin_amdgcn_readlane((unsigned)(d01 >> 32), b);
            cur0 |= (1ull << b) | (((unsigned long long)ah << 32) | al);
            cur1 |= (((unsigned long long)bh << 32) | bl);
        }
        // ---- phase B: drain block g1 keeps ----
        if (!done) {
            for (;;) {
                const unsigned long long nd = (~cur1) & valid1;
                if (!nd) break;
                const int b = __builtin_ctzll(nd);
                if (lane == 0 && cnt < 300) sKept[cnt] = g1 * 64 + b;
                ++cnt;
                kb1 |= (1ull << b);
                if (cnt >= 300) { done = 1; break; }
                const unsigned cl = __builtin_amdgcn_readlane((unsigned)d11, b);
                const unsigned ch = __builtin_amdgcn_readlane((unsigned)(d11 >> 32), b);
                cur1 |= (1ull << b) | (((unsigned long long)ch << 32) | cl);
            }
        }
        if (lane == 0) { sKeepW[g0] = kb0; sKeepW[g1] = kb1; }

        // ---- batched kept-row loads for BOTH blocks, one rem update ----
        if (!done && (kb0 | kb1)) {
            unsigned long long a0 = 0ull, a1 = 0ull;
            {
                int kbit[KSLOT];
                unsigned long long t = kb0;
                #pragma unroll
                for (int s = 0; s < KSLOT; ++s) {
                    kbit[s] = t ? __builtin_ctzll(t) : 64;
                    t &= t - 1;
                }
                #pragma unroll
                for (int s = 0; s < KSLOT; ++s) {
                    if (kbit[s] < 64) {            // wave-uniform branch
                        const unsigned long long* pr =
                            mask + (size_t)(g0 * 64 + kbit[s]) * MW;
                        a0 |= pr[lane];
                        a1 |= (lane < MASKW - 64) ? pr[64 + lane] : 0ull;
                    }
                }
                while (t) {                         // >KSLOT overflow (rare)
                    const int b = __builtin_ctzll(t); t &= t - 1;
                    const unsigned long long* pr =
                        mask + (size_t)(g0 * 64 + b) * MW;
                    a0 |= pr[lane];
                    a1 |= (lane < MASKW - 64) ? pr[64 + lane] : 0ull;
                }
            }
            {
                int kbit[KSLOT];
                unsigned long long t = kb1;
                #pragma unroll
                for (int s = 0; s < KSLOT; ++s) {
                    kbit[s] = t ? __builtin_ctzll(t) : 64;
                    t &= t - 1;
                }
                #pragma unroll
                for (int s = 0; s < KSLOT; ++s) {
                    if (kbit[s] < 64) {            // wave-uniform branch
                        const unsigned long long* pr =
                            mask + (size_t)(g1 * 64 + kbit[s]) * MW;
                        a0 |= pr[lane];
                        a1 |= (lane < MASKW - 64) ? pr[64 + lane] : 0ull;
                    }
                }
                while (t) {                         // >KSLOT overflow (rare)
                    const int b = __builtin_ctzll(t); t &= t - 1;
                    const unsigned long long* pr =
                        mask + (size_t)(g1 * 64 + b) * MW;
                    a0 |= pr[lane];
                    a1 |= (lane < MASKW - 64) ? pr[64 + lane] : 0ull;
                }
            }
            rem0 |= a0;
            rem1 |= a1;
        }
        d00 = n00; d01 = n01; d11 = n11;
    }

    __syncthreads();

    if (cnt < 300) {                                 // filler: unkept, asc index
        int c = cnt;
        for (int g = 0; g < MASKW && c < 300; ++g) {
            const unsigned long long valid =
                (g == MASKW - 1) ? 0x0000FFFFFFFFFFFFull : ~0ull;
            unsigned long long u = (~sKeepW[g]) & valid;
            while (u && c < 300) {
                const int b = __builtin_ctzll(u); u &= u - 1;
                if (lane == 0) sKept[c] = g * 64 + b;
                ++c;
            }
        }
    }
    __syncthreads();

    for (int s = lane; s < 300; s += 64) {
        const float4 b = sb[sKept[s]];
        out[s * 4 + 0] = b.x;
        out[s * 4 + 1] = b.y;
        out[s * 4 + 2] = b.z - b.x + 1.0f;
        out[s * 4 + 3] = b.w - b.y + 1.0f;
    }
}

// ---------------------------------------------------------------------------
extern "C" void kernel_launch(void* const* d_in, const int* in_sizes, int n_in,
                              void* d_out, int out_size, void* d_ws, size_t ws_size,
                              hipStream_t stream)
{
    (void)in_sizes; (void)n_in; (void)out_size; (void)ws_size;
    const float* x   = (const float*)d_in[0] + (size_t)7 * 512 * NPIX; // batch 7
    const float* cw3 = (const float*)d_in[1];
    const float* cb3 = (const float*)d_in[2];
    const float* rw  = (const float*)d_in[3];
    const float* rb  = (const float*)d_in[4];
    const float* clw = (const float*)d_in[5];
    const float* clb = (const float*)d_in[6];
    float* out = (float*)d_out;

    char* p = (char*)d_ws;
    auto alloc = [&](size_t n) { char* r = p; p += (n + 255) & ~(size_t)255; return r; };
    float*  part2  = (float*)alloc((size_t)CS * 512 * NPIX * 4);  // 41 MB
    float*  wtV    = (float*)alloc((size_t)4608 * 512 * 4);       // 9.4 MB
    float*  xpad   = (float*)alloc((size_t)512 * PSL * 4);        // 5.5 MB
    float*  feat   = (float*)alloc((size_t)512 * NPIX * 4);       // 5.12 MB
    float*  regcls = (float*)alloc((size_t)54 * NPIX * 4);        // 0.54 MB
    float4* boxes  = (float4*)alloc((size_t)NANCH * 16);          // 0.36 MB
    unsigned long long* keys = (unsigned long long*)alloc((size_t)NKEY * 8);
    int*    rank   = (int*)alloc((size_t)NANCH * 4);
    float4* sboxes = (float4*)alloc((size_t)PRE * 16);
    unsigned long long* mask = (unsigned long long*)alloc((size_t)PRE * MW * 8); // 4.6 MB

    prepK         <<<1088, 256, 0, stream>>>(x, cw3, xpad, wtV);
    conv3x3_v11   <<<dim3(64, 5, CS), 256, 0, stream>>>(xpad, wtV, part2);
    reduce_leaky4 <<<512, 256, 0, stream>>>(part2, cb3, feat);
    conv1x1_heads <<<dim3(40, 3, 3), 256, 0, stream>>>(feat, rw, rb, clw, clb, regcls);
    decodeK       <<<88, 256, 0, stream>>>(regcls, boxes, keys, rank);
    rankK         <<<dim3(88, 8), 256, 0, stream>>>(keys, rank);
    scatterK      <<<88, 256, 0, stream>>>(boxes, rank, sboxes);
    nmsMaskK      <<<dim3(375, 4), 256, 0, stream>>>(sboxes, mask);
    nmsScanOutK   <<<1, 64, 0, stream>>>(mask, sboxes, out);
}